// Round 2
// baseline (1770.170 us; speedup 1.0000x reference)
//
#include <hip/hip_runtime.h>
#include <math.h>

// ---------------- problem constants ----------------
constexpr int cB  = 32;     // batch
constexpr int cC  = 62;     // channels (graph nodes)
constexpr int cT  = 1024;   // time
constexpr int cNT = 32;     // temporal filters
constexpr int cLT = 708;    // concat conv-pool length (247+240+221)
constexpr int cLT2= 354;    // after avgpool(1,2)
constexpr int cFD = 11328;  // NT * 354
constexpr int cNBC = cB*cC; // 1984 blocks for per-(b,c) kernels

// element counts
constexpr size_t FEAT_N = (size_t)cB*cNT*cC*cLT;   // 44,949,504 (~180 MB) - conv logs, then in-place pooled mix
constexpr size_t S_N    = (size_t)cB*cC*cC;        // 123,008
constexpr size_t OW_N   = (size_t)cB*cC*96;        // 190,464
constexpr size_t PART_N = (size_t)cNBC*64;         // 126,976
constexpr size_t ADJ_N  = S_N;
constexpr size_t HE_N   = (size_t)cB*cC*64;
constexpr size_t HP_N   = (size_t)cB*cC*32;
constexpr size_t SA_N   = HP_N;
constexpr size_t HPRE_N = (size_t)cB*32*64;

// ---------------- temporal conv + square + avgpool16/4 + log ----------------
template<int K, int L, int P, int G>
__device__ __forceinline__ void conv_branch(
    const float* xs, const float* wp, float bb,
    float* part, float* featp, float* tsumt, float* tsqt, int tid)
{
  float pacc = 0.f;
  if (tid < G) {
    int pos = 4*tid;
    float a0=bb,a1=bb,a2=bb,a3=bb;
    float x0=xs[pos],x1=xs[pos+1],x2=xs[pos+2],x3=xs[pos+3];
    #pragma unroll 16
    for (int i=0;i<K;i++){
      float w = wp[i];
      a0 = fmaf(x0,w,a0); a1 = fmaf(x1,w,a1);
      a2 = fmaf(x2,w,a2); a3 = fmaf(x3,w,a3);
      x0=x1; x1=x2; x2=x3; x3 = xs[pos+4+i];   // padded xs, dead loads read zeros
    }
    pacc  = (pos   < L ? a0*a0 : 0.f);
    pacc += (pos+1 < L ? a1*a1 : 0.f);
    pacc += (pos+2 < L ? a2*a2 : 0.f);
    pacc += (pos+3 < L ? a3*a3 : 0.f);
  }
  part[tid] = pacc;
  __syncthreads();
  float val=0.f, vsq=0.f;
  if (tid < P) {
    float pooled = (part[tid]+part[tid+1]+part[tid+2]+part[tid+3])*(1.f/16.f);
    val = logf(pooled);
    featp[tid] = val;
    vsq = val*val;
  }
  #pragma unroll
  for (int o=32;o>0;o>>=1){ val += __shfl_down(val,o,64); vsq += __shfl_down(vsq,o,64); }
  if ((tid&63)==0){ atomicAdd(tsumt,val); atomicAdd(tsqt,vsq); }
  __syncthreads();
}

__global__ __launch_bounds__(256) void k_conv(
    const float* __restrict__ x,
    const float* __restrict__ w1, const float* __restrict__ b1,
    const float* __restrict__ w2, const float* __restrict__ b2,
    const float* __restrict__ w3, const float* __restrict__ b3,
    float* __restrict__ feat, float* __restrict__ part1)
{
  __shared__ float xs[1152];
  __shared__ float wall[6528];
  __shared__ float part[256];
  __shared__ float tsum[32], tsq[32];
  int b = blockIdx.x / cC, c = blockIdx.x % cC;
  int tid = threadIdx.x;
  for (int i=tid;i<1152;i+=256) xs[i] = (i<1024) ? x[(size_t)(b*cC+c)*cT + i] : 0.f;
  for (int i=tid;i<800;i+=256)  wall[i]      = w1[i];
  for (int i=tid;i<1632;i+=256) wall[800+i]  = w2[i];
  for (int i=tid;i<4096;i+=256) wall[2432+i] = w3[i];
  if (tid<32){ tsum[tid]=0.f; tsq[tid]=0.f; }
  __syncthreads();
  for (int t=0;t<32;t++){
    size_t base = ((size_t)(b*cNT+t)*cC + c)*cLT;
    conv_branch<25,1000,247,250>(xs, wall + t*25,         b1[t], part, feat+base,     &tsum[t], &tsq[t], tid);
    conv_branch<51,974,240,244>(xs, wall + 800 + t*51,    b2[t], part, feat+base+247, &tsum[t], &tsq[t], tid);
    conv_branch<128,897,221,225>(xs, wall + 2432 + t*128, b3[t], part, feat+base+487, &tsum[t], &tsq[t], tid);
  }
  if (tid<32){
    part1[(size_t)blockIdx.x*64 + tid*2]   = tsum[tid];
    part1[(size_t)blockIdx.x*64 + tid*2+1] = tsq[tid];
  }
}

// ---------------- partial-stat reduction: [nblk][nch][2] f32 -> [nch][2] f64 ----------------
__global__ __launch_bounds__(256) void k_reduce_stats(
    const float* __restrict__ part, double* __restrict__ stat, int nblk, int nch)
{
  int ch = blockIdx.x, tid = threadIdx.x;
  double s=0,q=0;
  for (int i=tid;i<nblk;i+=256){
    s += (double)part[(size_t)i*nch*2 + ch*2];
    q += (double)part[(size_t)i*nch*2 + ch*2 + 1];
  }
  __shared__ double ls[256], lq[256];
  ls[tid]=s; lq[tid]=q; __syncthreads();
  for (int o=128;o>0;o>>=1){ if(tid<o){ls[tid]+=ls[tid+o]; lq[tid]+=lq[tid+o];} __syncthreads(); }
  if (tid==0){ stat[ch*2]=ls[0]; stat[ch*2+1]=lq[0]; }
}

// ---------------- BN_t + 1x1 conv + leaky + avgpool(1,2)  --- IN-PLACE into feat rows ----------------
// Block (b,c) reads feat[(b,t,c, 118*ch .. +118)] and writes pooled output to
// feat[(b,o,c, 59*ch .. +59)] -- always strictly below all future reads of this block,
// and no other block touches (b,*,c,*) rows.
__global__ __launch_bounds__(256) void k_mix(
    float* __restrict__ feat, const double* __restrict__ stat1,
    const float* __restrict__ oxo_w, const float* __restrict__ oxo_b,
    float* __restrict__ part2)
{
  __shared__ float ft[32*118];
  __shared__ float wsh[32*33];
  __shared__ float mvm[32], mvi[32];
  __shared__ float osum[32], osq[32];
  int b = blockIdx.x / cC, c = blockIdx.x % cC;
  int tid = threadIdx.x;
  for (int i=tid;i<1024;i+=256){ int o=i>>5, t=i&31; wsh[o*33+t]=oxo_w[i]; }
  if (tid<32){
    double cnt = (double)cB*cC*cLT;
    double m = stat1[tid*2]/cnt;
    double v = stat1[tid*2+1]/cnt - m*m;
    mvm[tid] = (float)m;
    mvi[tid] = (float)(1.0/sqrt(v+1e-5));
    osum[tid]=0.f; osq[tid]=0.f;
  }
  int o = tid >> 3, lg = tid & 7;
  float ob = oxo_b[o];
  float accs=0.f, accq=0.f;
  for (int ch=0; ch<6; ch++){
    __syncthreads();
    int l0 = ch*118;
    for (int i=tid;i<32*118;i+=256){
      int t = i/118, l = i-t*118;
      ft[i] = (feat[((size_t)(b*cNT+t)*cC + c)*cLT + l0 + l] - mvm[t]) * mvi[t];
    }
    __syncthreads();
    for (int l2=lg; l2<59; l2+=8){
      float m0=ob, m1=ob;
      #pragma unroll 8
      for (int t=0;t<32;t++){
        float w = wsh[o*33+t];
        m0 = fmaf(ft[t*118 + 2*l2],   w, m0);
        m1 = fmaf(ft[t*118 + 2*l2+1], w, m1);
      }
      m0 = m0>0.f ? m0 : 0.01f*m0;
      m1 = m1>0.f ? m1 : 0.01f*m1;
      float v = 0.5f*(m0+m1);
      feat[((size_t)(b*cNT+o)*cC + c)*cLT + ch*59 + l2] = v;
      accs += v; accq += v*v;
    }
  }
  atomicAdd(&osum[o], accs);
  atomicAdd(&osq[o], accq);
  __syncthreads();
  if (tid<32){
    part2[(size_t)blockIdx.x*64 + tid*2]   = osum[tid];
    part2[(size_t)blockIdx.x*64 + tid*2+1] = osq[tid];
  }
}

// ---------------- local-filter stats: per-c sum/sq of relu(bn2(raw)*lf_w - lf_b) ----------------
__global__ __launch_bounds__(256) void k_lfstats(
    const float* __restrict__ featbuf, const double* __restrict__ stat2,
    const float* __restrict__ lf_w, const float* __restrict__ lf_b,
    double* __restrict__ statC)
{
  __shared__ float mvm[32], mvi[32];
  __shared__ float rs[256], rq[256];
  int b = blockIdx.x / cC, c = blockIdx.x % cC;
  int tid = threadIdx.x;
  if (tid<32){
    double cnt = (double)cB*cC*cLT2;
    double m = stat2[tid*2]/cnt;
    double v = stat2[tid*2+1]/cnt - m*m;
    mvm[tid]=(float)m; mvi[tid]=(float)(1.0/sqrt(v+1e-5));
  }
  __syncthreads();
  float lb = lf_b[c];
  float s=0.f,q=0.f;
  for (int f=tid; f<cFD; f+=256){
    int t = f/cLT2, l2 = f - t*cLT2;
    float raw = featbuf[((size_t)(b*cNT+t)*cC + c)*cLT + l2];
    float z = (raw - mvm[t])*mvi[t];
    float v = fmaxf(fmaf(z, lf_w[(size_t)c*cFD + f], -lb), 0.f);
    s += v; q = fmaf(v,v,q);
  }
  rs[tid]=s; rq[tid]=q; __syncthreads();
  for (int o=128;o>0;o>>=1){ if(tid<o){rs[tid]+=rs[tid+o];rq[tid]+=rq[tid+o];} __syncthreads(); }
  if (tid==0){ atomicAdd(&statC[c*2],(double)rs[0]); atomicAdd(&statC[c*2+1],(double)rq[0]); }
}

// ---------------- gram: s[b] = outN[b] @ outN[b]^T (lf + both BNs fused into loader) ----------------
__global__ __launch_bounds__(256) void k_gram(
    const float* __restrict__ featbuf, const double* __restrict__ stat2,
    const float* __restrict__ lf_w, const float* __restrict__ lf_b,
    const double* __restrict__ statC, float* __restrict__ s_out)
{
  __shared__ float lt[64*68];
  __shared__ float m2s[32], i2s[32];
  __shared__ float mC[64], iC[64], lbs[64];
  int b = blockIdx.x >> 3, ks = blockIdx.x & 7;
  int tid = threadIdx.x;
  if (tid<32){
    double cnt = (double)cB*cC*cLT2;
    double m = stat2[tid*2]/cnt;
    double v = stat2[tid*2+1]/cnt - m*m;
    m2s[tid]=(float)m; i2s[tid]=(float)(1.0/sqrt(v+1e-5));
  }
  if (tid<64){
    if (tid<62){
      double cnt = (double)cB*cFD;
      double m = statC[tid*2]/cnt;
      double v = statC[tid*2+1]/cnt - m*m;
      mC[tid]=(float)m; iC[tid]=(float)(1.0/sqrt(v+1e-5));
      lbs[tid]=lf_b[tid];
    } else { mC[tid]=0.f; iC[tid]=0.f; lbs[tid]=0.f; }
  }
  float acc[4][4] = {{0.f}};
  int n0 = (tid>>4)<<2;
  int m0 = (tid&15)<<2;
  int kk = tid & 63, nr = tid >> 6;
  for (int tile=ks; tile<177; tile+=8){
    int k0 = tile<<6;
    int f = k0 + kk, t = f/cLT2, l2 = f - t*cLT2;
    __syncthreads();
    for (int n=nr; n<64; n+=4){
      float v = 0.f;
      if (n<62){
        float raw = featbuf[((size_t)(b*cNT+t)*cC + n)*cLT + l2];
        float z = (raw - m2s[t])*i2s[t];
        float val = fmaxf(fmaf(z, lf_w[(size_t)n*cFD + f], -lbs[n]), 0.f);
        v = (val - mC[n]) * iC[n];
      }
      lt[kk*68 + n] = v;
    }
    __syncthreads();
    #pragma unroll 8
    for (int k=0;k<64;k++){
      const float4 av = *(const float4*)&lt[k*68 + n0];
      const float4 bv = *(const float4*)&lt[k*68 + m0];
      acc[0][0]=fmaf(av.x,bv.x,acc[0][0]); acc[0][1]=fmaf(av.x,bv.y,acc[0][1]);
      acc[0][2]=fmaf(av.x,bv.z,acc[0][2]); acc[0][3]=fmaf(av.x,bv.w,acc[0][3]);
      acc[1][0]=fmaf(av.y,bv.x,acc[1][0]); acc[1][1]=fmaf(av.y,bv.y,acc[1][1]);
      acc[1][2]=fmaf(av.y,bv.z,acc[1][2]); acc[1][3]=fmaf(av.y,bv.w,acc[1][3]);
      acc[2][0]=fmaf(av.z,bv.x,acc[2][0]); acc[2][1]=fmaf(av.z,bv.y,acc[2][1]);
      acc[2][2]=fmaf(av.z,bv.z,acc[2][2]); acc[2][3]=fmaf(av.z,bv.w,acc[2][3]);
      acc[3][0]=fmaf(av.w,bv.x,acc[3][0]); acc[3][1]=fmaf(av.w,bv.y,acc[3][1]);
      acc[3][2]=fmaf(av.w,bv.z,acc[3][2]); acc[3][3]=fmaf(av.w,bv.w,acc[3][3]);
    }
  }
  for (int i=0;i<4;i++) if (n0+i<62)
    for (int j=0;j<4;j++) if (m0+j<62)
      atomicAdd(&s_out[((size_t)b*cC + n0+i)*cC + m0+j], acc[i][j]);
}

// ---------------- ow = outN @ [entry_w | pool_w]  (K=11328, N=96; lf fused in loader) ----------------
__global__ __launch_bounds__(256) void k_ow(
    const float* __restrict__ featbuf, const double* __restrict__ stat2,
    const float* __restrict__ lf_w, const float* __restrict__ lf_b,
    const double* __restrict__ statC,
    const float* __restrict__ entry_w, const float* __restrict__ pool_w,
    float* __restrict__ ow)
{
  __shared__ float lt[64*68];
  __shared__ float lw[64*100];
  __shared__ float m2s[32], i2s[32];
  __shared__ float mC[64], iC[64], lbs[64];
  int b = blockIdx.x >> 3, ks = blockIdx.x & 7;
  int tid = threadIdx.x;
  if (tid<32){
    double cnt = (double)cB*cC*cLT2;
    double m = stat2[tid*2]/cnt;
    double v = stat2[tid*2+1]/cnt - m*m;
    m2s[tid]=(float)m; i2s[tid]=(float)(1.0/sqrt(v+1e-5));
  }
  if (tid<64){
    if (tid<62){
      double cnt = (double)cB*cFD;
      double m = statC[tid*2]/cnt;
      double v = statC[tid*2+1]/cnt - m*m;
      mC[tid]=(float)m; iC[tid]=(float)(1.0/sqrt(v+1e-5));
      lbs[tid]=lf_b[tid];
    } else { mC[tid]=0.f; iC[tid]=0.f; lbs[tid]=0.f; }
  }
  float acc[4][6] = {{0.f}};
  int n0 = (tid>>4)<<2;
  int m0 = (tid&15)*6;
  int kk = tid & 63, nr = tid >> 6;
  for (int tile=ks; tile<177; tile+=8){
    int k0 = tile<<6;
    int f = k0 + kk, t = f/cLT2, l2 = f - t*cLT2;
    __syncthreads();
    for (int n=nr;n<64;n+=4){
      float v=0.f;
      if (n<62){
        float raw = featbuf[((size_t)(b*cNT+t)*cC + n)*cLT + l2];
        float z = (raw - m2s[t])*i2s[t];
        float val = fmaxf(fmaf(z, lf_w[(size_t)n*cFD + f], -lbs[n]), 0.f);
        v = (val - mC[n]) * iC[n];
      }
      lt[kk*68+n]=v;
    }
    for (int i=tid;i<6144;i+=256){
      int kw = i/96, j = i-kw*96;
      float wv = (j<64) ? entry_w[(size_t)(k0+kw)*64 + j] : pool_w[(size_t)(k0+kw)*32 + (j-64)];
      lw[kw*100 + j] = wv;
    }
    __syncthreads();
    #pragma unroll 4
    for (int k=0;k<64;k++){
      const float4 av = *(const float4*)&lt[k*68+n0];
      const float2 w0 = *(const float2*)&lw[k*100+m0];
      const float2 w1 = *(const float2*)&lw[k*100+m0+2];
      const float2 w2 = *(const float2*)&lw[k*100+m0+4];
      float wv[6] = {w0.x,w0.y,w1.x,w1.y,w2.x,w2.y};
      float avv[4] = {av.x,av.y,av.z,av.w};
      #pragma unroll
      for (int i=0;i<4;i++)
        #pragma unroll
        for (int j=0;j<6;j++)
          acc[i][j] = fmaf(avv[i], wv[j], acc[i][j]);
    }
  }
  for (int i=0;i<4;i++) if (n0+i<62)
    for (int j=0;j<6;j++)
      atomicAdd(&ow[((size_t)b*cC + n0+i)*96 + m0+j], acc[i][j]);
}

// ---------------- adjacency build + sym normalization ----------------
__global__ __launch_bounds__(256) void k_adj(
    const float* __restrict__ s, const float* __restrict__ gadj,
    float* __restrict__ adj)
{
  __shared__ float a[3844];
  __shared__ float dsh[62];
  int b = blockIdx.x, tid = threadIdx.x;
  for (int i=tid;i<3844;i+=256){
    int n=i/62, m=i-n*62;
    float g = gadj[n*62+m] + gadj[m*62+n];
    float v = s[(size_t)b*3844+i]*g;
    v = v>0.f ? v : 0.f;
    if (n==m) v += 1.f;
    a[i]=v;
  }
  __syncthreads();
  if (tid<62){
    float rsum=0.f;
    for (int m=0;m<62;m++) rsum += a[tid*62+m];
    if (rsum==0.f) rsum=1.f;
    dsh[tid] = 1.0f/sqrtf(rsum);
  }
  __syncthreads();
  for (int i=tid;i<3844;i+=256){
    int n=i/62, m=i-n*62;
    adj[(size_t)b*3844+i] = a[i]*dsh[n]*dsh[m];
  }
}

// ---------------- h_entry_pre / h_pool_pre = adj @ ow - bias, + node stats ----------------
__global__ __launch_bounds__(256) void k_gcn1(
    const float* __restrict__ adj, const float* __restrict__ ow,
    const float* __restrict__ entry_b, const float* __restrict__ pool_b,
    float* __restrict__ hE, float* __restrict__ hP,
    double* __restrict__ statE, double* __restrict__ statP)
{
  __shared__ float aL[3844];
  __shared__ float oL[5952];
  __shared__ float es[62], eq[62], ps[62], pq[62];
  int b = blockIdx.x, tid = threadIdx.x;
  for (int i=tid;i<3844;i+=256) aL[i]=adj[(size_t)b*3844+i];
  for (int i=tid;i<5952;i+=256) oL[i]=ow[(size_t)b*5952+i];
  if (tid<62){es[tid]=0.f;eq[tid]=0.f;ps[tid]=0.f;pq[tid]=0.f;}
  __syncthreads();
  for (int i=tid;i<5952;i+=256){
    int n=i/96, j=i-n*96;
    float v=0.f;
    for (int m=0;m<62;m++) v = fmaf(aL[n*62+m], oL[m*96+j], v);
    if (j<64){
      v -= entry_b[j];
      hE[((size_t)b*62+n)*64 + j] = v;
      atomicAdd(&es[n],v); atomicAdd(&eq[n],v*v);
    } else {
      int j2=j-64;
      v -= pool_b[j2];
      hP[((size_t)b*62+n)*32 + j2] = v;
      atomicAdd(&ps[n],v); atomicAdd(&pq[n],v*v);
    }
  }
  __syncthreads();
  if (tid<62){
    atomicAdd(&statE[tid*2],(double)es[tid]);
    atomicAdd(&statE[tid*2+1],(double)eq[tid]);
    atomicAdd(&statP[tid*2],(double)ps[tid]);
    atomicAdd(&statP[tid*2+1],(double)pq[tid]);
  }
}

// ---------------- normalize h_entry in place ----------------
__global__ __launch_bounds__(256) void k_bn_he(float* __restrict__ hE,
                                               const double* __restrict__ statE)
{
  int idx = blockIdx.x*256 + threadIdx.x;
  if (idx >= cB*62*64) return;
  int n = (idx>>6) % 62;
  double cnt = (double)cB*64;
  double m = statE[n*2]/cnt;
  double v = statE[n*2+1]/cnt - m*m;
  hE[idx] = (hE[idx]-(float)m) * (float)(1.0/sqrt(v+1e-5));
}

// ---------------- s_assign = softmax(bn(h_pool) @ pl_w + pl_b), + ent_loss ----------------
__global__ __launch_bounds__(256) void k_assign(
    const float* __restrict__ hP, const double* __restrict__ statP,
    const float* __restrict__ pl_w, const float* __restrict__ pl_b,
    float* __restrict__ sA, double* __restrict__ accs)
{
  int gid = blockIdx.x*256 + threadIdx.x;
  int r = gid >> 5, o = gid & 31;
  int n = r % 62;
  double cnt = (double)cB*32;
  double md = statP[n*2]/cnt;
  double vd = statP[n*2+1]/cnt - md*md;
  float m = (float)md, inv = (float)(1.0/sqrt(vd+1e-5));
  float y = pl_b[o];
  for (int j=0;j<32;j++){
    float z = (hP[(size_t)r*32+j]-m)*inv;
    y = fmaf(z, pl_w[j*32+o], y);
  }
  float mx = y;
  for (int d=16;d>0;d>>=1) mx = fmaxf(mx, __shfl_xor(mx,d,32));
  float e = expf(y-mx);
  float sum = e;
  for (int d=16;d>0;d>>=1) sum += __shfl_xor(sum,d,32);
  float p = e/sum;
  sA[(size_t)r*32+o] = p;
  float ent = -p*logf(p+1e-30f);
  for (int d=16;d>0;d>>=1) ent += __shfl_xor(ent,d,32);
  if (o==0) atomicAdd(&accs[1], (double)ent);
}

// ---------------- dense_diff_pool + embed GCN pre + link_loss ----------------
__global__ __launch_bounds__(256) void k_pool(
    const float* __restrict__ adj, const float* __restrict__ sA_g,
    const float* __restrict__ hE, const float* __restrict__ embed_w,
    const float* __restrict__ embed_b, float* __restrict__ hpre,
    double* __restrict__ statH, double* __restrict__ accs)
{
  __shared__ float aL[3844];
  __shared__ float sL[1984];
  __shared__ float hL[3968];   // later reused as e1[32*64]
  __shared__ float t1[1984];   // later reused as sT[32*62]
  __shared__ float xp[2048];
  __shared__ float ap[1024];
  __shared__ float red[256];
  __shared__ float ksum[32], ksq[32];
  float* e1 = hL;
  float* sT = t1;
  int b = blockIdx.x, tid = threadIdx.x;
  for (int i=tid;i<3844;i+=256) aL[i]=adj[(size_t)b*3844+i];
  for (int i=tid;i<1984;i+=256) sL[i]=sA_g[(size_t)b*1984+i];
  for (int i=tid;i<3968;i+=256) hL[i]=hE[(size_t)b*3968+i];
  if (tid<32){ksum[tid]=0.f;ksq[tid]=0.f;}
  __syncthreads();
  for (int i=tid;i<2048;i+=256){
    int k=i>>6, f=i&63;
    float v=0.f;
    for (int n=0;n<62;n++) v = fmaf(sL[n*32+k], hL[n*64+f], v);
    xp[i]=v;
  }
  for (int i=tid;i<1984;i+=256){
    int n=i>>5, k=i&31;
    float v=0.f;
    for (int m=0;m<62;m++) v = fmaf(aL[n*62+m], sL[m*32+k], v);
    t1[i]=v;
  }
  __syncthreads();
  for (int i=tid;i<1024;i+=256){
    int k=i>>5, l=i&31;
    float v=0.f;
    for (int n=0;n<62;n++) v = fmaf(sL[n*32+k], t1[n*32+l], v);
    ap[i]=v;
  }
  __syncthreads();
  for (int i=tid;i<1984;i+=256){
    int k=i/62, n=i-k*62;
    sT[k*62+n] = sL[n*32+k];
  }
  __syncthreads();
  float lacc=0.f;
  for (int i=tid;i<3844;i+=256){
    int n=i/62, m=i-n*62;
    float v=0.f;
    for (int k=0;k<32;k++) v = fmaf(sT[k*62+n], sT[k*62+m], v);
    float d = aL[i]-v+1e-30f;
    lacc = fmaf(d,d,lacc);
  }
  red[tid]=lacc; __syncthreads();
  for (int o=128;o>0;o>>=1){ if(tid<o) red[tid]+=red[tid+o]; __syncthreads(); }
  if (tid==0) atomicAdd(&accs[0], (double)red[0]);
  __syncthreads();
  for (int i=tid;i<2048;i+=256){
    int k=i>>6, f=i&63;
    float v=0.f;
    for (int l=0;l<32;l++) v = fmaf(ap[k*32+l], xp[l*64+f], v);
    e1[i]=v;
  }
  __syncthreads();
  for (int i=tid;i<2048;i+=256){
    int k=i>>6, j=i&63;
    float v=0.f;
    for (int f=0;f<64;f++) v = fmaf(e1[k*64+f], embed_w[f*64+j], v);
    v -= embed_b[j];
    hpre[(size_t)b*2048 + i] = v;
    atomicAdd(&ksum[k], v);
    atomicAdd(&ksq[k], v*v);
  }
  __syncthreads();
  if (tid<32){
    atomicAdd(&statH[tid*2],   (double)ksum[tid]);
    atomicAdd(&statH[tid*2+1], (double)ksq[tid]);
  }
}

// ---------------- reps + MLP head (pre final BN) ----------------
__global__ __launch_bounds__(128) void k_head(
    const float* __restrict__ hE, const float* __restrict__ hpre,
    const double* __restrict__ statH,
    const float* __restrict__ fc1_w, const float* __restrict__ fc1_b,
    const float* __restrict__ fc2_w, const float* __restrict__ fc2_b,
    const float* __restrict__ fc3_w, const float* __restrict__ fc3_b,
    float* __restrict__ o_pre)
{
  __shared__ float o1[128], y1[128], y2[64];
  __shared__ float mk[32], ik[32];
  int b = blockIdx.x, tid = threadIdx.x;
  if (tid<32){
    double cnt = 2048.0;
    double m = statH[tid*2]/cnt;
    double v = statH[tid*2+1]/cnt - m*m;
    mk[tid]=(float)m; ik[tid]=(float)(1.0/sqrt(v+1e-5));
  }
  __syncthreads();
  if (tid<64){
    float s1=0.f;
    for (int n=0;n<62;n++) s1 += hE[((size_t)b*62+n)*64+tid];
    o1[tid]=s1;
    float s2=0.f;
    for (int k=0;k<32;k++) s2 += (hpre[(size_t)b*2048 + k*64+tid]-mk[k])*ik[k];
    o1[64+tid]=s2;
  }
  __syncthreads();
  {
    float y = fc1_b[tid];
    for (int j=0;j<128;j++) y = fmaf(o1[j], fc1_w[j*128+tid], y);
    y1[tid] = fmaxf(y,0.f);
  }
  __syncthreads();
  if (tid<64){
    float z = fc2_b[tid];
    for (int j=0;j<128;j++) z = fmaf(y1[j], fc2_w[j*64+tid], z);
    y2[tid]=fmaxf(z,0.f);
  }
  __syncthreads();
  if (tid<4){
    float w = fc3_b[tid];
    for (int j=0;j<64;j++) w = fmaf(y2[j], fc3_w[j*4+tid], w);
    o_pre[b*4+tid]=w;
  }
}

// ---------------- final BN over batch + losses ----------------
__global__ void k_final(const float* __restrict__ o_pre, const double* __restrict__ accs,
                        float* __restrict__ out)
{
  int tid = threadIdx.x;
  if (tid<4){
    float s=0.f,q=0.f;
    for (int b=0;b<32;b++){ float v=o_pre[b*4+tid]; s+=v; q+=v*v; }
    float m = s*(1.f/32.f);
    float var = q*(1.f/32.f) - m*m;
    float inv = 1.0f/sqrtf(var+1e-5f);
    for (int b=0;b<32;b++) out[b*4+tid] = (o_pre[b*4+tid]-m)*inv;
  }
  if (tid==4) out[128] = (float)(sqrt(accs[0])/123008.0);
  if (tid==5) out[129] = (float)(accs[1]/1984.0);
}

// ---------------- workspace-too-small sentinel (diagnostic) ----------------
__global__ void k_wsfail(float* __restrict__ out, int n)
{
  int i = blockIdx.x*256 + threadIdx.x;
  if (i < n) out[i] = 12345.0f;
}

// ============================================================================
extern "C" void kernel_launch(void* const* d_in, const int* in_sizes, int n_in,
                              void* d_out, int out_size, void* d_ws, size_t ws_size,
                              hipStream_t stream)
{
  const float* x       = (const float*)d_in[0];
  const float* w1      = (const float*)d_in[1];
  const float* b1      = (const float*)d_in[2];
  const float* w2      = (const float*)d_in[3];
  const float* b2      = (const float*)d_in[4];
  const float* w3      = (const float*)d_in[5];
  const float* b3      = (const float*)d_in[6];
  const float* oxo_w   = (const float*)d_in[7];
  const float* oxo_b   = (const float*)d_in[8];
  const float* lf_w    = (const float*)d_in[9];
  const float* lf_b    = (const float*)d_in[10];
  const float* gadj    = (const float*)d_in[11];
  const float* entry_w = (const float*)d_in[12];
  const float* entry_b = (const float*)d_in[13];
  const float* pool_w  = (const float*)d_in[14];
  const float* pool_b  = (const float*)d_in[15];
  const float* pl_w    = (const float*)d_in[16];
  const float* pl_b    = (const float*)d_in[17];
  const float* embed_w = (const float*)d_in[18];
  const float* embed_b = (const float*)d_in[19];
  const float* fc1_w   = (const float*)d_in[20];
  const float* fc1_b   = (const float*)d_in[21];
  const float* fc2_w   = (const float*)d_in[22];
  const float* fc2_b   = (const float*)d_in[23];
  const float* fc3_w   = (const float*)d_in[24];
  const float* fc3_b   = (const float*)d_in[25];

  char* ws = (char*)d_ws;
  size_t off = 0;
  auto take = [&](size_t bytes){ size_t o = off; off = (off + bytes + 15) & ~(size_t)15; return o; };

  size_t feat_o = take(FEAT_N*4);          // conv logs; k_mix writes pooled rows in place
  size_t zstart = off;                     // ---- zeroed zone (atomic accumulators) ----
  size_t s_o     = take(S_N*4);
  size_t ow_o    = take(OW_N*4);
  size_t statC_o = take(124*8);
  size_t statE_o = take(124*8);
  size_t statP_o = take(124*8);
  size_t statH_o = take(64*8);
  size_t accs_o  = take(2*8);
  size_t zend = off;                       // ---- end zeroed zone ----
  size_t stat1_o = take(64*8);
  size_t stat2_o = take(64*8);
  size_t part1_o = take(PART_N*4);
  size_t part2_o = take(PART_N*4);
  size_t adj_o   = take(ADJ_N*4);
  size_t hE_o    = take(HE_N*4);
  size_t hP_o    = take(HP_N*4);
  size_t sA_o    = take(SA_N*4);
  size_t hpre_o  = take(HPRE_N*4);
  size_t opre_o  = take(128*4);

  if (off > ws_size) {                     // diagnostic: ws too small
    k_wsfail<<<(out_size+255)/256, 256, 0, stream>>>((float*)d_out, out_size);
    return;
  }

  float*  feat  = (float*)(ws+feat_o);
  float*  s_g   = (float*)(ws+s_o);
  float*  ow_g  = (float*)(ws+ow_o);
  double* statC = (double*)(ws+statC_o);
  double* statE = (double*)(ws+statE_o);
  double* statP = (double*)(ws+statP_o);
  double* statH = (double*)(ws+statH_o);
  double* accs  = (double*)(ws+accs_o);
  double* stat1 = (double*)(ws+stat1_o);
  double* stat2 = (double*)(ws+stat2_o);
  float*  part1 = (float*)(ws+part1_o);
  float*  part2 = (float*)(ws+part2_o);
  float*  adj_g = (float*)(ws+adj_o);
  float*  hE_g  = (float*)(ws+hE_o);
  float*  hP_g  = (float*)(ws+hP_o);
  float*  sA_g  = (float*)(ws+sA_o);
  float*  hpre  = (float*)(ws+hpre_o);
  float*  opre  = (float*)(ws+opre_o);
  float*  out   = (float*)d_out;

  hipMemsetAsync(ws + zstart, 0, zend - zstart, stream);

  k_conv<<<cNBC, 256, 0, stream>>>(x, w1,b1, w2,b2, w3,b3, feat, part1);
  k_reduce_stats<<<32, 256, 0, stream>>>(part1, stat1, cNBC, 32);
  k_mix<<<cNBC, 256, 0, stream>>>(feat, stat1, oxo_w, oxo_b, part2);
  k_reduce_stats<<<32, 256, 0, stream>>>(part2, stat2, cNBC, 32);
  k_lfstats<<<cNBC, 256, 0, stream>>>(feat, stat2, lf_w, lf_b, statC);
  k_gram<<<cB*8, 256, 0, stream>>>(feat, stat2, lf_w, lf_b, statC, s_g);
  k_ow<<<cB*8, 256, 0, stream>>>(feat, stat2, lf_w, lf_b, statC, entry_w, pool_w, ow_g);
  k_adj<<<cB, 256, 0, stream>>>(s_g, gadj, adj_g);
  k_gcn1<<<cB, 256, 0, stream>>>(adj_g, ow_g, entry_b, pool_b, hE_g, hP_g, statE, statP);
  k_bn_he<<<(cB*62*64+255)/256, 256, 0, stream>>>(hE_g, statE);
  k_assign<<<(cB*62*32)/256, 256, 0, stream>>>(hP_g, statP, pl_w, pl_b, sA_g, accs);
  k_pool<<<cB, 256, 0, stream>>>(adj_g, sA_g, hE_g, embed_w, embed_b, hpre, statH, accs);
  k_head<<<cB, 128, 0, stream>>>(hE_g, hpre, statH, fc1_w, fc1_b, fc2_w, fc2_b, fc3_w, fc3_b, opre);
  k_final<<<1, 64, 0, stream>>>(opre, accs, out);
}

// Round 3
// 1526.526 us; speedup vs baseline: 1.1596x; 1.1596x over previous
//
#include <hip/hip_runtime.h>
#include <math.h>

// ---------------- problem constants ----------------
constexpr int cB  = 32;     // batch
constexpr int cC  = 62;     // channels (graph nodes)
constexpr int cT  = 1024;   // time
constexpr int cNT = 32;     // temporal filters
constexpr int cLT = 708;    // concat conv-pool length (247+240+221)
constexpr int cLT2= 354;    // after avgpool(1,2)
constexpr int cFD = 11328;  // NT * 354
constexpr int cNBC = cB*cC; // 1984 blocks for per-(b,c) kernels

// element counts
constexpr size_t FEAT_N = (size_t)cB*cNT*cC*cLT;   // ~180 MB - conv logs, then in-place pooled mix
constexpr size_t S_N    = (size_t)cB*cC*cC;
constexpr size_t OW_N   = (size_t)cB*cC*96;
constexpr size_t PART_N = (size_t)cNBC*64;
constexpr size_t ADJ_N  = S_N;
constexpr size_t HE_N   = (size_t)cB*cC*64;
constexpr size_t HP_N   = (size_t)cB*cC*32;
constexpr size_t SA_N   = HP_N;
constexpr size_t HPRE_N = (size_t)cB*32*64;

// ---------------- temporal conv core: K4 padded taps, rolling float4 window ----------------
// x-read: ds_read_b128 at 16B/lane stride (conflict-free); w-read: broadcast float4.
template<int K4, int L, int G>
__device__ __forceinline__ void conv_core(
    const float* xs, const float* wp, float bb, float* part, int tid)
{
  float pacc = 0.f;
  if (tid < G) {
    int pos = 4*tid;
    float4 c = *(const float4*)&xs[pos];
    float x0=c.x, x1=c.y, x2=c.z, x3=c.w;
    float a0=bb, a1=bb, a2=bb, a3=bb;
    #pragma unroll
    for (int i=0;i<K4;i+=4){
      float4 w = *(const float4*)&wp[i];          // uniform addr -> LDS broadcast
      float4 n = *(const float4*)&xs[pos+4+i];    // 16B aligned, stride-16B lanes
      a0=fmaf(x0,w.x,a0); a1=fmaf(x1,w.x,a1); a2=fmaf(x2,w.x,a2); a3=fmaf(x3,w.x,a3);
      a0=fmaf(x1,w.y,a0); a1=fmaf(x2,w.y,a1); a2=fmaf(x3,w.y,a2); a3=fmaf(n.x,w.y,a3);
      a0=fmaf(x2,w.z,a0); a1=fmaf(x3,w.z,a1); a2=fmaf(n.x,w.z,a2); a3=fmaf(n.y,w.z,a3);
      a0=fmaf(x3,w.w,a0); a1=fmaf(n.x,w.w,a1); a2=fmaf(n.y,w.w,a2); a3=fmaf(n.z,w.w,a3);
      x0=n.x; x1=n.y; x2=n.z; x3=n.w;
    }
    pacc  = (pos   < L ? a0*a0 : 0.f);
    pacc += (pos+1 < L ? a1*a1 : 0.f);
    pacc += (pos+2 < L ? a2*a2 : 0.f);
    pacc += (pos+3 < L ? a3*a3 : 0.f);
  }
  part[tid] = pacc;
}

// pooled = avg16 of squares (stride 4) -> log -> store; accumulate stats
template<int P>
__device__ __forceinline__ void pool_log(
    const float* part, float* featp, int tid, float& val, float& vsq)
{
  if (tid < P) {
    float pooled = (part[tid]+part[tid+1]+part[tid+2]+part[tid+3])*(1.f/16.f);
    float lv = logf(pooled);
    featp[tid] = lv;
    val += lv; vsq += lv*lv;
  }
}

__global__ __launch_bounds__(256) void k_conv(
    const float* __restrict__ x,
    const float* __restrict__ w1, const float* __restrict__ b1,
    const float* __restrict__ w2, const float* __restrict__ b2,
    const float* __restrict__ w3, const float* __restrict__ b3,
    float* __restrict__ feat, float* __restrict__ part1)
{
  __shared__ float xs[1152];
  __shared__ float wall[32*28 + 32*52 + 32*128];  // 6656, padded filters, 16B-aligned strides
  __shared__ float pt1[256], pt2[256], pt3[256];
  __shared__ float tsum[32], tsq[32];
  int b = blockIdx.x / cC, c = blockIdx.x % cC;
  int tid = threadIdx.x;
  for (int i=tid;i<1152;i+=256) xs[i] = (i<1024) ? x[(size_t)(b*cC+c)*cT + i] : 0.f;
  for (int i=tid;i<896;i+=256){  int t=i/28, k=i-t*28; wall[i]      = (k<25)? w1[t*25+k] : 0.f; }
  for (int i=tid;i<1664;i+=256){ int t=i/52, k=i-t*52; wall[896+i]  = (k<51)? w2[t*51+k] : 0.f; }
  for (int i=tid;i<4096;i+=256){ wall[2560+i] = w3[i]; }
  if (tid<32){ tsum[tid]=0.f; tsq[tid]=0.f; }
  for (int t=0;t<32;t++){
    __syncthreads();   // covers initial staging on t=0; part reuse afterwards
    conv_core<28,1000,250>(xs, wall + t*28,        b1[t], pt1, tid);
    conv_core<52,974,244> (xs, wall + 896 + t*52,  b2[t], pt2, tid);
    conv_core<128,897,225>(xs, wall + 2560 + t*128,b3[t], pt3, tid);
    __syncthreads();
    size_t base = ((size_t)(b*cNT+t)*cC + c)*cLT;
    float val=0.f, vsq=0.f;
    pool_log<247>(pt1, feat+base,     tid, val, vsq);
    pool_log<240>(pt2, feat+base+247, tid, val, vsq);
    pool_log<221>(pt3, feat+base+487, tid, val, vsq);
    #pragma unroll
    for (int o=32;o>0;o>>=1){ val += __shfl_down(val,o,64); vsq += __shfl_down(vsq,o,64); }
    if ((tid&63)==0){ atomicAdd(&tsum[t],val); atomicAdd(&tsq[t],vsq); }
  }
  __syncthreads();
  if (tid<32){
    part1[(size_t)blockIdx.x*64 + tid*2]   = tsum[tid];
    part1[(size_t)blockIdx.x*64 + tid*2+1] = tsq[tid];
  }
}

// ---------------- partial-stat reduction: [nblk][nch][2] f32 -> [nch][2] f64 ----------------
__global__ __launch_bounds__(256) void k_reduce_stats(
    const float* __restrict__ part, double* __restrict__ stat, int nblk, int nch)
{
  int ch = blockIdx.x, tid = threadIdx.x;
  double s=0,q=0;
  for (int i=tid;i<nblk;i+=256){
    s += (double)part[(size_t)i*nch*2 + ch*2];
    q += (double)part[(size_t)i*nch*2 + ch*2 + 1];
  }
  __shared__ double ls[256], lq[256];
  ls[tid]=s; lq[tid]=q; __syncthreads();
  for (int o=128;o>0;o>>=1){ if(tid<o){ls[tid]+=ls[tid+o]; lq[tid]+=lq[tid+o];} __syncthreads(); }
  if (tid==0){ stat[ch*2]=ls[0]; stat[ch*2+1]=lq[0]; }
}

// ---------------- BN_t + 1x1 conv + leaky + avgpool(1,2)  --- IN-PLACE into feat rows ----------------
__global__ __launch_bounds__(256) void k_mix(
    float* __restrict__ feat, const double* __restrict__ stat1,
    const float* __restrict__ oxo_w, const float* __restrict__ oxo_b,
    float* __restrict__ part2)
{
  __shared__ float ft[32*118];
  __shared__ float wsh[32*33];
  __shared__ float mvm[32], mvi[32];
  __shared__ float osum[32], osq[32];
  int b = blockIdx.x / cC, c = blockIdx.x % cC;
  int tid = threadIdx.x;
  for (int i=tid;i<1024;i+=256){ int o=i>>5, t=i&31; wsh[o*33+t]=oxo_w[i]; }
  if (tid<32){
    double cnt = (double)cB*cC*cLT;
    double m = stat1[tid*2]/cnt;
    double v = stat1[tid*2+1]/cnt - m*m;
    mvm[tid] = (float)m;
    mvi[tid] = (float)(1.0/sqrt(v+1e-5));
    osum[tid]=0.f; osq[tid]=0.f;
  }
  int o = tid >> 3, lg = tid & 7;
  float ob = oxo_b[o];
  float accs=0.f, accq=0.f;
  for (int ch=0; ch<6; ch++){
    __syncthreads();
    int l0 = ch*118;
    for (int i=tid;i<32*118;i+=256){
      int t = i/118, l = i-t*118;
      ft[i] = (feat[((size_t)(b*cNT+t)*cC + c)*cLT + l0 + l] - mvm[t]) * mvi[t];
    }
    __syncthreads();
    for (int l2=lg; l2<59; l2+=8){
      float m0=ob, m1=ob;
      #pragma unroll 8
      for (int t=0;t<32;t++){
        float w = wsh[o*33+t];
        m0 = fmaf(ft[t*118 + 2*l2],   w, m0);
        m1 = fmaf(ft[t*118 + 2*l2+1], w, m1);
      }
      m0 = m0>0.f ? m0 : 0.01f*m0;
      m1 = m1>0.f ? m1 : 0.01f*m1;
      float v = 0.5f*(m0+m1);
      feat[((size_t)(b*cNT+o)*cC + c)*cLT + ch*59 + l2] = v;
      accs += v; accq += v*v;
    }
  }
  atomicAdd(&osum[o], accs);
  atomicAdd(&osq[o], accq);
  __syncthreads();
  if (tid<32){
    part2[(size_t)blockIdx.x*64 + tid*2]   = osum[tid];
    part2[(size_t)blockIdx.x*64 + tid*2+1] = osq[tid];
  }
}

// ---------------- local-filter stats: per-c sum/sq of relu(bn2(raw)*lf_w - lf_b) ----------------
__global__ __launch_bounds__(256) void k_lfstats(
    const float* __restrict__ featbuf, const double* __restrict__ stat2,
    const float* __restrict__ lf_w, const float* __restrict__ lf_b,
    double* __restrict__ statC)
{
  __shared__ float mvm[32], mvi[32];
  __shared__ float rs[256], rq[256];
  int b = blockIdx.x / cC, c = blockIdx.x % cC;
  int tid = threadIdx.x;
  if (tid<32){
    double cnt = (double)cB*cC*cLT2;
    double m = stat2[tid*2]/cnt;
    double v = stat2[tid*2+1]/cnt - m*m;
    mvm[tid]=(float)m; mvi[tid]=(float)(1.0/sqrt(v+1e-5));
  }
  __syncthreads();
  float lb = lf_b[c];
  float s=0.f,q=0.f;
  for (int f=tid; f<cFD; f+=256){
    int t = f/cLT2, l2 = f - t*cLT2;
    float raw = featbuf[((size_t)(b*cNT+t)*cC + c)*cLT + l2];
    float z = (raw - mvm[t])*mvi[t];
    float v = fmaxf(fmaf(z, lf_w[(size_t)c*cFD + f], -lb), 0.f);
    s += v; q = fmaf(v,v,q);
  }
  rs[tid]=s; rq[tid]=q; __syncthreads();
  for (int o=128;o>0;o>>=1){ if(tid<o){rs[tid]+=rs[tid+o];rq[tid]+=rq[tid+o];} __syncthreads(); }
  if (tid==0){ atomicAdd(&statC[c*2],(double)rs[0]); atomicAdd(&statC[c*2+1],(double)rq[0]); }
}

// ---------------- gram: s[b] = outN[b] @ outN[b]^T (lf + both BNs fused into loader) ----------------
__global__ __launch_bounds__(256) void k_gram(
    const float* __restrict__ featbuf, const double* __restrict__ stat2,
    const float* __restrict__ lf_w, const float* __restrict__ lf_b,
    const double* __restrict__ statC, float* __restrict__ s_out)
{
  __shared__ float lt[64*68];
  __shared__ float m2s[32], i2s[32];
  __shared__ float mC[64], iC[64], lbs[64];
  int b = blockIdx.x >> 3, ks = blockIdx.x & 7;
  int tid = threadIdx.x;
  if (tid<32){
    double cnt = (double)cB*cC*cLT2;
    double m = stat2[tid*2]/cnt;
    double v = stat2[tid*2+1]/cnt - m*m;
    m2s[tid]=(float)m; i2s[tid]=(float)(1.0/sqrt(v+1e-5));
  }
  if (tid<64){
    if (tid<62){
      double cnt = (double)cB*cFD;
      double m = statC[tid*2]/cnt;
      double v = statC[tid*2+1]/cnt - m*m;
      mC[tid]=(float)m; iC[tid]=(float)(1.0/sqrt(v+1e-5));
      lbs[tid]=lf_b[tid];
    } else { mC[tid]=0.f; iC[tid]=0.f; lbs[tid]=0.f; }
  }
  float acc[4][4] = {{0.f}};
  int n0 = (tid>>4)<<2;
  int m0 = (tid&15)<<2;
  int kk = tid & 63, nr = tid >> 6;
  for (int tile=ks; tile<177; tile+=8){
    int k0 = tile<<6;
    int f = k0 + kk, t = f/cLT2, l2 = f - t*cLT2;
    __syncthreads();
    for (int n=nr; n<64; n+=4){
      float v = 0.f;
      if (n<62){
        float raw = featbuf[((size_t)(b*cNT+t)*cC + n)*cLT + l2];
        float z = (raw - m2s[t])*i2s[t];
        float val = fmaxf(fmaf(z, lf_w[(size_t)n*cFD + f], -lbs[n]), 0.f);
        v = (val - mC[n]) * iC[n];
      }
      lt[kk*68 + n] = v;
    }
    __syncthreads();
    #pragma unroll 8
    for (int k=0;k<64;k++){
      const float4 av = *(const float4*)&lt[k*68 + n0];
      const float4 bv = *(const float4*)&lt[k*68 + m0];
      acc[0][0]=fmaf(av.x,bv.x,acc[0][0]); acc[0][1]=fmaf(av.x,bv.y,acc[0][1]);
      acc[0][2]=fmaf(av.x,bv.z,acc[0][2]); acc[0][3]=fmaf(av.x,bv.w,acc[0][3]);
      acc[1][0]=fmaf(av.y,bv.x,acc[1][0]); acc[1][1]=fmaf(av.y,bv.y,acc[1][1]);
      acc[1][2]=fmaf(av.y,bv.z,acc[1][2]); acc[1][3]=fmaf(av.y,bv.w,acc[1][3]);
      acc[2][0]=fmaf(av.z,bv.x,acc[2][0]); acc[2][1]=fmaf(av.z,bv.y,acc[2][1]);
      acc[2][2]=fmaf(av.z,bv.z,acc[2][2]); acc[2][3]=fmaf(av.z,bv.w,acc[2][3]);
      acc[3][0]=fmaf(av.w,bv.x,acc[3][0]); acc[3][1]=fmaf(av.w,bv.y,acc[3][1]);
      acc[3][2]=fmaf(av.w,bv.z,acc[3][2]); acc[3][3]=fmaf(av.w,bv.w,acc[3][3]);
    }
  }
  for (int i=0;i<4;i++) if (n0+i<62)
    for (int j=0;j<4;j++) if (m0+j<62)
      atomicAdd(&s_out[((size_t)b*cC + n0+i)*cC + m0+j], acc[i][j]);
}

// ---------------- ow = outN @ [entry_w | pool_w]  (K=11328, N=96; lf fused in loader) ----------------
__global__ __launch_bounds__(256) void k_ow(
    const float* __restrict__ featbuf, const double* __restrict__ stat2,
    const float* __restrict__ lf_w, const float* __restrict__ lf_b,
    const double* __restrict__ statC,
    const float* __restrict__ entry_w, const float* __restrict__ pool_w,
    float* __restrict__ ow)
{
  __shared__ float lt[64*68];
  __shared__ float lw[64*100];
  __shared__ float m2s[32], i2s[32];
  __shared__ float mC[64], iC[64], lbs[64];
  int b = blockIdx.x >> 3, ks = blockIdx.x & 7;
  int tid = threadIdx.x;
  if (tid<32){
    double cnt = (double)cB*cC*cLT2;
    double m = stat2[tid*2]/cnt;
    double v = stat2[tid*2+1]/cnt - m*m;
    m2s[tid]=(float)m; i2s[tid]=(float)(1.0/sqrt(v+1e-5));
  }
  if (tid<64){
    if (tid<62){
      double cnt = (double)cB*cFD;
      double m = statC[tid*2]/cnt;
      double v = statC[tid*2+1]/cnt - m*m;
      mC[tid]=(float)m; iC[tid]=(float)(1.0/sqrt(v+1e-5));
      lbs[tid]=lf_b[tid];
    } else { mC[tid]=0.f; iC[tid]=0.f; lbs[tid]=0.f; }
  }
  float acc[4][6] = {{0.f}};
  int n0 = (tid>>4)<<2;
  int m0 = (tid&15)*6;
  int kk = tid & 63, nr = tid >> 6;
  for (int tile=ks; tile<177; tile+=8){
    int k0 = tile<<6;
    int f = k0 + kk, t = f/cLT2, l2 = f - t*cLT2;
    __syncthreads();
    for (int n=nr;n<64;n+=4){
      float v=0.f;
      if (n<62){
        float raw = featbuf[((size_t)(b*cNT+t)*cC + n)*cLT + l2];
        float z = (raw - m2s[t])*i2s[t];
        float val = fmaxf(fmaf(z, lf_w[(size_t)n*cFD + f], -lbs[n]), 0.f);
        v = (val - mC[n]) * iC[n];
      }
      lt[kk*68+n]=v;
    }
    for (int i=tid;i<6144;i+=256){
      int kw = i/96, j = i-kw*96;
      float wv = (j<64) ? entry_w[(size_t)(k0+kw)*64 + j] : pool_w[(size_t)(k0+kw)*32 + (j-64)];
      lw[kw*100 + j] = wv;
    }
    __syncthreads();
    #pragma unroll 4
    for (int k=0;k<64;k++){
      const float4 av = *(const float4*)&lt[k*68+n0];
      const float2 w0 = *(const float2*)&lw[k*100+m0];
      const float2 w1 = *(const float2*)&lw[k*100+m0+2];
      const float2 w2 = *(const float2*)&lw[k*100+m0+4];
      float wv[6] = {w0.x,w0.y,w1.x,w1.y,w2.x,w2.y};
      float avv[4] = {av.x,av.y,av.z,av.w};
      #pragma unroll
      for (int i=0;i<4;i++)
        #pragma unroll
        for (int j=0;j<6;j++)
          acc[i][j] = fmaf(avv[i], wv[j], acc[i][j]);
    }
  }
  for (int i=0;i<4;i++) if (n0+i<62)
    for (int j=0;j<6;j++)
      atomicAdd(&ow[((size_t)b*cC + n0+i)*96 + m0+j], acc[i][j]);
}

// ---------------- adjacency build + sym normalization ----------------
__global__ __launch_bounds__(256) void k_adj(
    const float* __restrict__ s, const float* __restrict__ gadj,
    float* __restrict__ adj)
{
  __shared__ float a[3844];
  __shared__ float dsh[62];
  int b = blockIdx.x, tid = threadIdx.x;
  for (int i=tid;i<3844;i+=256){
    int n=i/62, m=i-n*62;
    float g = gadj[n*62+m] + gadj[m*62+n];
    float v = s[(size_t)b*3844+i]*g;
    v = v>0.f ? v : 0.f;
    if (n==m) v += 1.f;
    a[i]=v;
  }
  __syncthreads();
  if (tid<62){
    float rsum=0.f;
    for (int m=0;m<62;m++) rsum += a[tid*62+m];
    if (rsum==0.f) rsum=1.f;
    dsh[tid] = 1.0f/sqrtf(rsum);
  }
  __syncthreads();
  for (int i=tid;i<3844;i+=256){
    int n=i/62, m=i-n*62;
    adj[(size_t)b*3844+i] = a[i]*dsh[n]*dsh[m];
  }
}

// ---------------- h_entry_pre / h_pool_pre = adj @ ow - bias, + node stats ----------------
__global__ __launch_bounds__(256) void k_gcn1(
    const float* __restrict__ adj, const float* __restrict__ ow,
    const float* __restrict__ entry_b, const float* __restrict__ pool_b,
    float* __restrict__ hE, float* __restrict__ hP,
    double* __restrict__ statE, double* __restrict__ statP)
{
  __shared__ float aL[3844];
  __shared__ float oL[5952];
  __shared__ float es[62], eq[62], ps[62], pq[62];
  int b = blockIdx.x, tid = threadIdx.x;
  for (int i=tid;i<3844;i+=256) aL[i]=adj[(size_t)b*3844+i];
  for (int i=tid;i<5952;i+=256) oL[i]=ow[(size_t)b*5952+i];
  if (tid<62){es[tid]=0.f;eq[tid]=0.f;ps[tid]=0.f;pq[tid]=0.f;}
  __syncthreads();
  for (int i=tid;i<5952;i+=256){
    int n=i/96, j=i-n*96;
    float v=0.f;
    for (int m=0;m<62;m++) v = fmaf(aL[n*62+m], oL[m*96+j], v);
    if (j<64){
      v -= entry_b[j];
      hE[((size_t)b*62+n)*64 + j] = v;
      atomicAdd(&es[n],v); atomicAdd(&eq[n],v*v);
    } else {
      int j2=j-64;
      v -= pool_b[j2];
      hP[((size_t)b*62+n)*32 + j2] = v;
      atomicAdd(&ps[n],v); atomicAdd(&pq[n],v*v);
    }
  }
  __syncthreads();
  if (tid<62){
    atomicAdd(&statE[tid*2],(double)es[tid]);
    atomicAdd(&statE[tid*2+1],(double)eq[tid]);
    atomicAdd(&statP[tid*2],(double)ps[tid]);
    atomicAdd(&statP[tid*2+1],(double)pq[tid]);
  }
}

// ---------------- normalize h_entry in place ----------------
__global__ __launch_bounds__(256) void k_bn_he(float* __restrict__ hE,
                                               const double* __restrict__ statE)
{
  int idx = blockIdx.x*256 + threadIdx.x;
  if (idx >= cB*62*64) return;
  int n = (idx>>6) % 62;
  double cnt = (double)cB*64;
  double m = statE[n*2]/cnt;
  double v = statE[n*2+1]/cnt - m*m;
  hE[idx] = (hE[idx]-(float)m) * (float)(1.0/sqrt(v+1e-5));
}

// ---------------- s_assign = softmax(bn(h_pool) @ pl_w + pl_b), + ent_loss ----------------
__global__ __launch_bounds__(256) void k_assign(
    const float* __restrict__ hP, const double* __restrict__ statP,
    const float* __restrict__ pl_w, const float* __restrict__ pl_b,
    float* __restrict__ sA, double* __restrict__ accs)
{
  int gid = blockIdx.x*256 + threadIdx.x;
  int r = gid >> 5, o = gid & 31;
  int n = r % 62;
  double cnt = (double)cB*32;
  double md = statP[n*2]/cnt;
  double vd = statP[n*2+1]/cnt - md*md;
  float m = (float)md, inv = (float)(1.0/sqrt(vd+1e-5));
  float y = pl_b[o];
  for (int j=0;j<32;j++){
    float z = (hP[(size_t)r*32+j]-m)*inv;
    y = fmaf(z, pl_w[j*32+o], y);
  }
  float mx = y;
  for (int d=16;d>0;d>>=1) mx = fmaxf(mx, __shfl_xor(mx,d,32));
  float e = expf(y-mx);
  float sum = e;
  for (int d=16;d>0;d>>=1) sum += __shfl_xor(sum,d,32);
  float p = e/sum;
  sA[(size_t)r*32+o] = p;
  float ent = -p*logf(p+1e-30f);
  for (int d=16;d>0;d>>=1) ent += __shfl_xor(ent,d,32);
  if (o==0) atomicAdd(&accs[1], (double)ent);
}

// ---------------- dense_diff_pool + embed GCN pre + link_loss ----------------
__global__ __launch_bounds__(256) void k_pool(
    const float* __restrict__ adj, const float* __restrict__ sA_g,
    const float* __restrict__ hE, const float* __restrict__ embed_w,
    const float* __restrict__ embed_b, float* __restrict__ hpre,
    double* __restrict__ statH, double* __restrict__ accs)
{
  __shared__ float aL[3844];
  __shared__ float sL[1984];
  __shared__ float hL[3968];   // later reused as e1[32*64]
  __shared__ float t1[1984];   // later reused as sT[32*62]
  __shared__ float xp[2048];
  __shared__ float ap[1024];
  __shared__ float red[256];
  __shared__ float ksum[32], ksq[32];
  float* e1 = hL;
  float* sT = t1;
  int b = blockIdx.x, tid = threadIdx.x;
  for (int i=tid;i<3844;i+=256) aL[i]=adj[(size_t)b*3844+i];
  for (int i=tid;i<1984;i+=256) sL[i]=sA_g[(size_t)b*1984+i];
  for (int i=tid;i<3968;i+=256) hL[i]=hE[(size_t)b*3968+i];
  if (tid<32){ksum[tid]=0.f;ksq[tid]=0.f;}
  __syncthreads();
  for (int i=tid;i<2048;i+=256){
    int k=i>>6, f=i&63;
    float v=0.f;
    for (int n=0;n<62;n++) v = fmaf(sL[n*32+k], hL[n*64+f], v);
    xp[i]=v;
  }
  for (int i=tid;i<1984;i+=256){
    int n=i>>5, k=i&31;
    float v=0.f;
    for (int m=0;m<62;m++) v = fmaf(aL[n*62+m], sL[m*32+k], v);
    t1[i]=v;
  }
  __syncthreads();
  for (int i=tid;i<1024;i+=256){
    int k=i>>5, l=i&31;
    float v=0.f;
    for (int n=0;n<62;n++) v = fmaf(sL[n*32+k], t1[n*32+l], v);
    ap[i]=v;
  }
  __syncthreads();
  for (int i=tid;i<1984;i+=256){
    int k=i/62, n=i-k*62;
    sT[k*62+n] = sL[n*32+k];
  }
  __syncthreads();
  float lacc=0.f;
  for (int i=tid;i<3844;i+=256){
    int n=i/62, m=i-n*62;
    float v=0.f;
    for (int k=0;k<32;k++) v = fmaf(sT[k*62+n], sT[k*62+m], v);
    float d = aL[i]-v+1e-30f;
    lacc = fmaf(d,d,lacc);
  }
  red[tid]=lacc; __syncthreads();
  for (int o=128;o>0;o>>=1){ if(tid<o) red[tid]+=red[tid+o]; __syncthreads(); }
  if (tid==0) atomicAdd(&accs[0], (double)red[0]);
  __syncthreads();
  for (int i=tid;i<2048;i+=256){
    int k=i>>6, f=i&63;
    float v=0.f;
    for (int l=0;l<32;l++) v = fmaf(ap[k*32+l], xp[l*64+f], v);
    e1[i]=v;
  }
  __syncthreads();
  for (int i=tid;i<2048;i+=256){
    int k=i>>6, j=i&63;
    float v=0.f;
    for (int f=0;f<64;f++) v = fmaf(e1[k*64+f], embed_w[f*64+j], v);
    v -= embed_b[j];
    hpre[(size_t)b*2048 + i] = v;
    atomicAdd(&ksum[k], v);
    atomicAdd(&ksq[k], v*v);
  }
  __syncthreads();
  if (tid<32){
    atomicAdd(&statH[tid*2],   (double)ksum[tid]);
    atomicAdd(&statH[tid*2+1], (double)ksq[tid]);
  }
}

// ---------------- reps + MLP head (pre final BN) ----------------
__global__ __launch_bounds__(128) void k_head(
    const float* __restrict__ hE, const float* __restrict__ hpre,
    const double* __restrict__ statH,
    const float* __restrict__ fc1_w, const float* __restrict__ fc1_b,
    const float* __restrict__ fc2_w, const float* __restrict__ fc2_b,
    const float* __restrict__ fc3_w, const float* __restrict__ fc3_b,
    float* __restrict__ o_pre)
{
  __shared__ float o1[128], y1[128], y2[64];
  __shared__ float mk[32], ik[32];
  int b = blockIdx.x, tid = threadIdx.x;
  if (tid<32){
    double cnt = 2048.0;
    double m = statH[tid*2]/cnt;
    double v = statH[tid*2+1]/cnt - m*m;
    mk[tid]=(float)m; ik[tid]=(float)(1.0/sqrt(v+1e-5));
  }
  __syncthreads();
  if (tid<64){
    float s1=0.f;
    for (int n=0;n<62;n++) s1 += hE[((size_t)b*62+n)*64+tid];
    o1[tid]=s1;
    float s2=0.f;
    for (int k=0;k<32;k++) s2 += (hpre[(size_t)b*2048 + k*64+tid]-mk[k])*ik[k];
    o1[64+tid]=s2;
  }
  __syncthreads();
  {
    float y = fc1_b[tid];
    for (int j=0;j<128;j++) y = fmaf(o1[j], fc1_w[j*128+tid], y);
    y1[tid] = fmaxf(y,0.f);
  }
  __syncthreads();
  if (tid<64){
    float z = fc2_b[tid];
    for (int j=0;j<128;j++) z = fmaf(y1[j], fc2_w[j*64+tid], z);
    y2[tid]=fmaxf(z,0.f);
  }
  __syncthreads();
  if (tid<4){
    float w = fc3_b[tid];
    for (int j=0;j<64;j++) w = fmaf(y2[j], fc3_w[j*4+tid], w);
    o_pre[b*4+tid]=w;
  }
}

// ---------------- final BN over batch + losses ----------------
__global__ void k_final(const float* __restrict__ o_pre, const double* __restrict__ accs,
                        float* __restrict__ out)
{
  int tid = threadIdx.x;
  if (tid<4){
    float s=0.f,q=0.f;
    for (int b=0;b<32;b++){ float v=o_pre[b*4+tid]; s+=v; q+=v*v; }
    float m = s*(1.f/32.f);
    float var = q*(1.f/32.f) - m*m;
    float inv = 1.0f/sqrtf(var+1e-5f);
    for (int b=0;b<32;b++) out[b*4+tid] = (o_pre[b*4+tid]-m)*inv;
  }
  if (tid==4) out[128] = (float)(sqrt(accs[0])/123008.0);
  if (tid==5) out[129] = (float)(accs[1]/1984.0);
}

// ---------------- workspace-too-small sentinel (diagnostic) ----------------
__global__ void k_wsfail(float* __restrict__ out, int n)
{
  int i = blockIdx.x*256 + threadIdx.x;
  if (i < n) out[i] = 12345.0f;
}

// ============================================================================
extern "C" void kernel_launch(void* const* d_in, const int* in_sizes, int n_in,
                              void* d_out, int out_size, void* d_ws, size_t ws_size,
                              hipStream_t stream)
{
  const float* x       = (const float*)d_in[0];
  const float* w1      = (const float*)d_in[1];
  const float* b1      = (const float*)d_in[2];
  const float* w2      = (const float*)d_in[3];
  const float* b2      = (const float*)d_in[4];
  const float* w3      = (const float*)d_in[5];
  const float* b3      = (const float*)d_in[6];
  const float* oxo_w   = (const float*)d_in[7];
  const float* oxo_b   = (const float*)d_in[8];
  const float* lf_w    = (const float*)d_in[9];
  const float* lf_b    = (const float*)d_in[10];
  const float* gadj    = (const float*)d_in[11];
  const float* entry_w = (const float*)d_in[12];
  const float* entry_b = (const float*)d_in[13];
  const float* pool_w  = (const float*)d_in[14];
  const float* pool_b  = (const float*)d_in[15];
  const float* pl_w    = (const float*)d_in[16];
  const float* pl_b    = (const float*)d_in[17];
  const float* embed_w = (const float*)d_in[18];
  const float* embed_b = (const float*)d_in[19];
  const float* fc1_w   = (const float*)d_in[20];
  const float* fc1_b   = (const float*)d_in[21];
  const float* fc2_w   = (const float*)d_in[22];
  const float* fc2_b   = (const float*)d_in[23];
  const float* fc3_w   = (const float*)d_in[24];
  const float* fc3_b   = (const float*)d_in[25];

  char* ws = (char*)d_ws;
  size_t off = 0;
  auto take = [&](size_t bytes){ size_t o = off; off = (off + bytes + 15) & ~(size_t)15; return o; };

  size_t feat_o = take(FEAT_N*4);          // conv logs; k_mix writes pooled rows in place
  size_t zstart = off;                     // ---- zeroed zone (atomic accumulators) ----
  size_t s_o     = take(S_N*4);
  size_t ow_o    = take(OW_N*4);
  size_t statC_o = take(124*8);
  size_t statE_o = take(124*8);
  size_t statP_o = take(124*8);
  size_t statH_o = take(64*8);
  size_t accs_o  = take(2*8);
  size_t zend = off;                       // ---- end zeroed zone ----
  size_t stat1_o = take(64*8);
  size_t stat2_o = take(64*8);
  size_t part1_o = take(PART_N*4);
  size_t part2_o = take(PART_N*4);
  size_t adj_o   = take(ADJ_N*4);
  size_t hE_o    = take(HE_N*4);
  size_t hP_o    = take(HP_N*4);
  size_t sA_o    = take(SA_N*4);
  size_t hpre_o  = take(HPRE_N*4);
  size_t opre_o  = take(128*4);

  if (off > ws_size) {                     // diagnostic: ws too small
    k_wsfail<<<(out_size+255)/256, 256, 0, stream>>>((float*)d_out, out_size);
    return;
  }

  float*  feat  = (float*)(ws+feat_o);
  float*  s_g   = (float*)(ws+s_o);
  float*  ow_g  = (float*)(ws+ow_o);
  double* statC = (double*)(ws+statC_o);
  double* statE = (double*)(ws+statE_o);
  double* statP = (double*)(ws+statP_o);
  double* statH = (double*)(ws+statH_o);
  double* accs  = (double*)(ws+accs_o);
  double* stat1 = (double*)(ws+stat1_o);
  double* stat2 = (double*)(ws+stat2_o);
  float*  part1 = (float*)(ws+part1_o);
  float*  part2 = (float*)(ws+part2_o);
  float*  adj_g = (float*)(ws+adj_o);
  float*  hE_g  = (float*)(ws+hE_o);
  float*  hP_g  = (float*)(ws+hP_o);
  float*  sA_g  = (float*)(ws+sA_o);
  float*  hpre  = (float*)(ws+hpre_o);
  float*  opre  = (float*)(ws+opre_o);
  float*  out   = (float*)d_out;

  hipMemsetAsync(ws + zstart, 0, zend - zstart, stream);

  k_conv<<<cNBC, 256, 0, stream>>>(x, w1,b1, w2,b2, w3,b3, feat, part1);
  k_reduce_stats<<<32, 256, 0, stream>>>(part1, stat1, cNBC, 32);
  k_mix<<<cNBC, 256, 0, stream>>>(feat, stat1, oxo_w, oxo_b, part2);
  k_reduce_stats<<<32, 256, 0, stream>>>(part2, stat2, cNBC, 32);
  k_lfstats<<<cNBC, 256, 0, stream>>>(feat, stat2, lf_w, lf_b, statC);
  k_gram<<<cB*8, 256, 0, stream>>>(feat, stat2, lf_w, lf_b, statC, s_g);
  k_ow<<<cB*8, 256, 0, stream>>>(feat, stat2, lf_w, lf_b, statC, entry_w, pool_w, ow_g);
  k_adj<<<cB, 256, 0, stream>>>(s_g, gadj, adj_g);
  k_gcn1<<<cB, 256, 0, stream>>>(adj_g, ow_g, entry_b, pool_b, hE_g, hP_g, statE, statP);
  k_bn_he<<<(cB*62*64+255)/256, 256, 0, stream>>>(hE_g, statE);
  k_assign<<<(cB*62*32)/256, 256, 0, stream>>>(hP_g, statP, pl_w, pl_b, sA_g, accs);
  k_pool<<<cB, 256, 0, stream>>>(adj_g, sA_g, hE_g, embed_w, embed_b, hpre, statH, accs);
  k_head<<<cB, 128, 0, stream>>>(hE_g, hpre, statH, fc1_w, fc1_b, fc2_w, fc2_b, fc3_w, fc3_b, opre);
  k_final<<<1, 64, 0, stream>>>(opre, accs, out);
}

// Round 4
// 1005.248 us; speedup vs baseline: 1.7609x; 1.5186x over previous
//
#include <hip/hip_runtime.h>
#include <math.h>

// ---------------- problem constants ----------------
constexpr int cB  = 32;     // batch
constexpr int cC  = 62;     // channels (graph nodes)
constexpr int cT  = 1024;   // time
constexpr int cNT = 32;     // temporal filters
constexpr int cLT = 708;    // concat conv-pool length (247+240+221)
constexpr int cLT2= 354;    // after avgpool(1,2)
constexpr int cFD = 11328;  // NT * 354
constexpr int cNBC = cB*cC; // 1984 blocks for per-(b,c) kernels

// element counts
constexpr size_t FEAT_N = (size_t)cB*cNT*cC*cLT;   // ~180 MB - conv logs, then in-place pooled mix
constexpr size_t S_N    = (size_t)cB*cC*cC;
constexpr size_t OW_N   = (size_t)cB*cC*96;
constexpr size_t PART_N = (size_t)cNBC*64;
constexpr size_t ADJ_N  = S_N;
constexpr size_t HE_N   = (size_t)cB*cC*64;
constexpr size_t HP_N   = (size_t)cB*cC*32;
constexpr size_t SA_N   = HP_N;
constexpr size_t HPRE_N = (size_t)cB*32*64;
constexpr size_t WPAD_N = 32*28 + 32*52 + 32*128;  // 6656 padded weights

// ---------------- weight padding prep: zero-pad filters to 4-aligned tap counts ----------------
__global__ void k_padw(const float* __restrict__ w1, const float* __restrict__ w2,
                       const float* __restrict__ w3, float* __restrict__ wpad)
{
  int i = blockIdx.x*256 + threadIdx.x;
  if (i < 896){ int t=i/28, k=i-t*28; wpad[i] = (k<25) ? w1[t*25+k] : 0.f; }
  else if (i < 2560){ int j=i-896; int t=j/52, k=j-t*52; wpad[i] = (k<51) ? w2[t*51+k] : 0.f; }
  else if (i < 6656){ wpad[i] = w3[i-2560]; }
}

// ---------------- conv core: 4 filters x 4 positions per lane, rolling float4 window ----------------
// x: one ds_read_b128 per tap-quad shared by 4 filters; w: wave-uniform scalar loads (s_load).
template<int K4, int L, int G>
__device__ __forceinline__ void conv4(
    const float* xs, const float* __restrict__ wg, const float* __restrict__ bg,
    float* pt, int tid)
{
  if (tid >= G) return;
  int pos = 4*tid;
  float4 c = *(const float4*)&xs[pos];
  float x0=c.x, x1=c.y, x2=c.z, x3=c.w;
  float a[4][4];
  #pragma unroll
  for (int f=0;f<4;f++){ float bv=bg[f]; a[f][0]=bv; a[f][1]=bv; a[f][2]=bv; a[f][3]=bv; }
  #pragma unroll 2
  for (int i=0;i<K4;i+=4){
    float4 n = *(const float4*)&xs[pos+4+i];    // 16B-aligned, 16B/lane stride
    #pragma unroll
    for (int f=0;f<4;f++){
      const float* w = wg + f*K4 + i;           // wave-uniform -> scalar loads
      float w0=w[0], w1=w[1], w2=w[2], w3=w[3];
      a[f][0]=fmaf(x0,w0,a[f][0]); a[f][1]=fmaf(x1,w0,a[f][1]); a[f][2]=fmaf(x2,w0,a[f][2]); a[f][3]=fmaf(x3,w0,a[f][3]);
      a[f][0]=fmaf(x1,w1,a[f][0]); a[f][1]=fmaf(x2,w1,a[f][1]); a[f][2]=fmaf(x3,w1,a[f][2]); a[f][3]=fmaf(n.x,w1,a[f][3]);
      a[f][0]=fmaf(x2,w2,a[f][0]); a[f][1]=fmaf(x3,w2,a[f][1]); a[f][2]=fmaf(n.x,w2,a[f][2]); a[f][3]=fmaf(n.y,w2,a[f][3]);
      a[f][0]=fmaf(x3,w3,a[f][0]); a[f][1]=fmaf(n.x,w3,a[f][1]); a[f][2]=fmaf(n.y,w3,a[f][2]); a[f][3]=fmaf(n.z,w3,a[f][3]);
    }
    x0=n.x; x1=n.y; x2=n.z; x3=n.w;
  }
  #pragma unroll
  for (int f=0;f<4;f++){
    float p = (pos   < L ? a[f][0]*a[f][0] : 0.f)
            + (pos+1 < L ? a[f][1]*a[f][1] : 0.f)
            + (pos+2 < L ? a[f][2]*a[f][2] : 0.f)
            + (pos+3 < L ? a[f][3]*a[f][3] : 0.f);
    pt[f*256 + tid] = p;
  }
}

__global__ __launch_bounds__(256) void k_conv(
    const float* __restrict__ x,
    const float* __restrict__ wpad,
    const float* __restrict__ b1, const float* __restrict__ b2, const float* __restrict__ b3,
    float* __restrict__ feat, float* __restrict__ part1)
{
  __shared__ float xs[1152];
  __shared__ float pt1[1024], pt2[1024], pt3[1024];
  __shared__ float tsum[32], tsq[32];
  int b = blockIdx.x / cC, c = blockIdx.x % cC;
  int tid = threadIdx.x;
  for (int i=tid;i<1152;i+=256) xs[i] = (i<1024) ? x[(size_t)(b*cC+c)*cT + i] : 0.f;
  if (tid<32){ tsum[tid]=0.f; tsq[tid]=0.f; }
  for (int t0=0; t0<32; t0+=4){
    __syncthreads();   // covers initial staging (t0=0) and pt reuse afterwards
    conv4<28,1000,250>(xs, wpad + t0*28,        b1+t0, pt1, tid);
    conv4<52,974,244> (xs, wpad + 896 + t0*52,  b2+t0, pt2, tid);
    conv4<128,897,225>(xs, wpad + 2560 + t0*128,b3+t0, pt3, tid);
    __syncthreads();
    size_t base0 = ((size_t)(b*cNT+t0)*cC + c)*cLT;
    float val[4]={0.f,0.f,0.f,0.f}, vsq[4]={0.f,0.f,0.f,0.f};
    if (tid<247){
      #pragma unroll
      for (int f=0;f<4;f++){
        float p = (pt1[f*256+tid]+pt1[f*256+tid+1]+pt1[f*256+tid+2]+pt1[f*256+tid+3])*(1.f/16.f);
        float lv = logf(p);
        feat[base0 + (size_t)f*cC*cLT + tid] = lv;
        val[f]+=lv; vsq[f]+=lv*lv;
      }
    }
    if (tid<240){
      #pragma unroll
      for (int f=0;f<4;f++){
        float p = (pt2[f*256+tid]+pt2[f*256+tid+1]+pt2[f*256+tid+2]+pt2[f*256+tid+3])*(1.f/16.f);
        float lv = logf(p);
        feat[base0 + (size_t)f*cC*cLT + 247 + tid] = lv;
        val[f]+=lv; vsq[f]+=lv*lv;
      }
    }
    if (tid<221){
      #pragma unroll
      for (int f=0;f<4;f++){
        float p = (pt3[f*256+tid]+pt3[f*256+tid+1]+pt3[f*256+tid+2]+pt3[f*256+tid+3])*(1.f/16.f);
        float lv = logf(p);
        feat[base0 + (size_t)f*cC*cLT + 487 + tid] = lv;
        val[f]+=lv; vsq[f]+=lv*lv;
      }
    }
    #pragma unroll
    for (int f=0;f<4;f++){
      float v=val[f], q=vsq[f];
      #pragma unroll
      for (int o=32;o>0;o>>=1){ v += __shfl_down(v,o,64); q += __shfl_down(q,o,64); }
      if ((tid&63)==0){ atomicAdd(&tsum[t0+f], v); atomicAdd(&tsq[t0+f], q); }
    }
  }
  __syncthreads();
  if (tid<32){
    part1[(size_t)blockIdx.x*64 + tid*2]   = tsum[tid];
    part1[(size_t)blockIdx.x*64 + tid*2+1] = tsq[tid];
  }
}

// ---------------- partial-stat reduction: [nblk][nch][2] f32 -> [nch][2] f64 ----------------
__global__ __launch_bounds__(256) void k_reduce_stats(
    const float* __restrict__ part, double* __restrict__ stat, int nblk, int nch)
{
  int ch = blockIdx.x, tid = threadIdx.x;
  double s=0,q=0;
  for (int i=tid;i<nblk;i+=256){
    s += (double)part[(size_t)i*nch*2 + ch*2];
    q += (double)part[(size_t)i*nch*2 + ch*2 + 1];
  }
  __shared__ double ls[256], lq[256];
  ls[tid]=s; lq[tid]=q; __syncthreads();
  for (int o=128;o>0;o>>=1){ if(tid<o){ls[tid]+=ls[tid+o]; lq[tid]+=lq[tid+o];} __syncthreads(); }
  if (tid==0){ stat[ch*2]=ls[0]; stat[ch*2+1]=lq[0]; }
}

// ---------------- BN_t + 1x1 conv + leaky + avgpool(1,2)  --- IN-PLACE into feat rows ----------------
__global__ __launch_bounds__(256) void k_mix(
    float* __restrict__ feat, const double* __restrict__ stat1,
    const float* __restrict__ oxo_w, const float* __restrict__ oxo_b,
    float* __restrict__ part2)
{
  __shared__ float ft[32*118];
  __shared__ float wsh[32*33];
  __shared__ float mvm[32], mvi[32];
  __shared__ float osum[32], osq[32];
  int b = blockIdx.x / cC, c = blockIdx.x % cC;
  int tid = threadIdx.x;
  for (int i=tid;i<1024;i+=256){ int o=i>>5, t=i&31; wsh[o*33+t]=oxo_w[i]; }
  if (tid<32){
    double cnt = (double)cB*cC*cLT;
    double m = stat1[tid*2]/cnt;
    double v = stat1[tid*2+1]/cnt - m*m;
    mvm[tid] = (float)m;
    mvi[tid] = (float)(1.0/sqrt(v+1e-5));
    osum[tid]=0.f; osq[tid]=0.f;
  }
  int o = tid >> 3, lg = tid & 7;
  float ob = oxo_b[o];
  float accs=0.f, accq=0.f;
  for (int ch=0; ch<6; ch++){
    __syncthreads();
    int l0 = ch*118;
    for (int i=tid;i<32*118;i+=256){
      int t = i/118, l = i-t*118;
      ft[i] = (feat[((size_t)(b*cNT+t)*cC + c)*cLT + l0 + l] - mvm[t]) * mvi[t];
    }
    __syncthreads();
    for (int l2=lg; l2<59; l2+=8){
      float m0=ob, m1=ob;
      #pragma unroll 8
      for (int t=0;t<32;t++){
        float w = wsh[o*33+t];
        m0 = fmaf(ft[t*118 + 2*l2],   w, m0);
        m1 = fmaf(ft[t*118 + 2*l2+1], w, m1);
      }
      m0 = m0>0.f ? m0 : 0.01f*m0;
      m1 = m1>0.f ? m1 : 0.01f*m1;
      float v = 0.5f*(m0+m1);
      feat[((size_t)(b*cNT+o)*cC + c)*cLT + ch*59 + l2] = v;
      accs += v; accq += v*v;
    }
  }
  atomicAdd(&osum[o], accs);
  atomicAdd(&osq[o], accq);
  __syncthreads();
  if (tid<32){
    part2[(size_t)blockIdx.x*64 + tid*2]   = osum[tid];
    part2[(size_t)blockIdx.x*64 + tid*2+1] = osq[tid];
  }
}

// ---------------- local-filter stats: per-c sum/sq of relu(bn2(raw)*lf_w - lf_b) ----------------
__global__ __launch_bounds__(256) void k_lfstats(
    const float* __restrict__ featbuf, const double* __restrict__ stat2,
    const float* __restrict__ lf_w, const float* __restrict__ lf_b,
    double* __restrict__ statC)
{
  __shared__ float mvm[32], mvi[32];
  __shared__ float rs[256], rq[256];
  int b = blockIdx.x / cC, c = blockIdx.x % cC;
  int tid = threadIdx.x;
  if (tid<32){
    double cnt = (double)cB*cC*cLT2;
    double m = stat2[tid*2]/cnt;
    double v = stat2[tid*2+1]/cnt - m*m;
    mvm[tid]=(float)m; mvi[tid]=(float)(1.0/sqrt(v+1e-5));
  }
  __syncthreads();
  float lb = lf_b[c];
  float s=0.f,q=0.f;
  for (int f=tid; f<cFD; f+=256){
    int t = f/cLT2, l2 = f - t*cLT2;
    float raw = featbuf[((size_t)(b*cNT+t)*cC + c)*cLT + l2];
    float z = (raw - mvm[t])*mvi[t];
    float v = fmaxf(fmaf(z, lf_w[(size_t)c*cFD + f], -lb), 0.f);
    s += v; q = fmaf(v,v,q);
  }
  rs[tid]=s; rq[tid]=q; __syncthreads();
  for (int o=128;o>0;o>>=1){ if(tid<o){rs[tid]+=rs[tid+o];rq[tid]+=rq[tid+o];} __syncthreads(); }
  if (tid==0){ atomicAdd(&statC[c*2],(double)rs[0]); atomicAdd(&statC[c*2+1],(double)rq[0]); }
}

// ---------------- fused gram + ow: z staged once, both GEMMs accumulate ----------------
// s[b] = Z Z^T (62x62), ow[b] = Z @ [entry_w|pool_w] (62x96); Z computed in loader.
__global__ __launch_bounds__(256) void k_gramow(
    const float* __restrict__ featbuf, const double* __restrict__ stat2,
    const float* __restrict__ lf_w, const float* __restrict__ lf_b,
    const double* __restrict__ statC,
    const float* __restrict__ entry_w, const float* __restrict__ pool_w,
    float* __restrict__ s_out, float* __restrict__ ow)
{
  __shared__ float lt[64*68];
  __shared__ float lw[64*100];
  __shared__ float m2s[32], i2s[32];
  __shared__ float mC[64], iC[64], lbs[64];
  int b = blockIdx.x >> 4, ks = blockIdx.x & 15;
  int tid = threadIdx.x;
  if (tid<32){
    double cnt = (double)cB*cC*cLT2;
    double m = stat2[tid*2]/cnt;
    double v = stat2[tid*2+1]/cnt - m*m;
    m2s[tid]=(float)m; i2s[tid]=(float)(1.0/sqrt(v+1e-5));
  }
  if (tid<64){
    if (tid<62){
      double cnt = (double)cB*cFD;
      double m = statC[tid*2]/cnt;
      double v = statC[tid*2+1]/cnt - m*m;
      mC[tid]=(float)m; iC[tid]=(float)(1.0/sqrt(v+1e-5));
      lbs[tid]=lf_b[tid];
    } else { mC[tid]=0.f; iC[tid]=0.f; lbs[tid]=0.f; }
  }
  float accG[4][4] = {{0.f}};
  float accO[4][6] = {{0.f}};
  int n0 = (tid>>4)<<2;
  int mg = (tid&15)<<2;
  int jo = (tid&15)*6;
  int kk = tid & 63, nr = tid >> 6;
  for (int tile=ks; tile<177; tile+=16){
    int k0 = tile<<6;
    int f = k0 + kk, t = f/cLT2, l2 = f - t*cLT2;
    __syncthreads();
    for (int n=nr; n<64; n+=4){
      float v = 0.f;
      if (n<62){
        float raw = featbuf[((size_t)(b*cNT+t)*cC + n)*cLT + l2];
        float z = (raw - m2s[t])*i2s[t];
        float val = fmaxf(fmaf(z, lf_w[(size_t)n*cFD + f], -lbs[n]), 0.f);
        v = (val - mC[n]) * iC[n];
      }
      lt[kk*68 + n] = v;
    }
    for (int i=tid;i<6144;i+=256){
      int kw = i/96, j = i-kw*96;
      float wv = (j<64) ? entry_w[(size_t)(k0+kw)*64 + j] : pool_w[(size_t)(k0+kw)*32 + (j-64)];
      lw[kw*100 + j] = wv;
    }
    __syncthreads();
    #pragma unroll 4
    for (int k=0;k<64;k++){
      const float4 av = *(const float4*)&lt[k*68 + n0];
      const float4 bv = *(const float4*)&lt[k*68 + mg];
      const float2 w0 = *(const float2*)&lw[k*100+jo];
      const float2 w1 = *(const float2*)&lw[k*100+jo+2];
      const float2 w2 = *(const float2*)&lw[k*100+jo+4];
      float avv[4] = {av.x,av.y,av.z,av.w};
      float bvv[4] = {bv.x,bv.y,bv.z,bv.w};
      float wv[6]  = {w0.x,w0.y,w1.x,w1.y,w2.x,w2.y};
      #pragma unroll
      for (int i=0;i<4;i++){
        #pragma unroll
        for (int j=0;j<4;j++) accG[i][j] = fmaf(avv[i], bvv[j], accG[i][j]);
        #pragma unroll
        for (int j=0;j<6;j++) accO[i][j] = fmaf(avv[i], wv[j], accO[i][j]);
      }
    }
  }
  for (int i=0;i<4;i++) if (n0+i<62){
    for (int j=0;j<4;j++) if (mg+j<62)
      atomicAdd(&s_out[((size_t)b*cC + n0+i)*cC + mg+j], accG[i][j]);
    for (int j=0;j<6;j++)
      atomicAdd(&ow[((size_t)b*cC + n0+i)*96 + jo+j], accO[i][j]);
  }
}

// ---------------- adjacency build + sym normalization ----------------
__global__ __launch_bounds__(256) void k_adj(
    const float* __restrict__ s, const float* __restrict__ gadj,
    float* __restrict__ adj)
{
  __shared__ float a[3844];
  __shared__ float dsh[62];
  int b = blockIdx.x, tid = threadIdx.x;
  for (int i=tid;i<3844;i+=256){
    int n=i/62, m=i-n*62;
    float g = gadj[n*62+m] + gadj[m*62+n];
    float v = s[(size_t)b*3844+i]*g;
    v = v>0.f ? v : 0.f;
    if (n==m) v += 1.f;
    a[i]=v;
  }
  __syncthreads();
  if (tid<62){
    float rsum=0.f;
    for (int m=0;m<62;m++) rsum += a[tid*62+m];
    if (rsum==0.f) rsum=1.f;
    dsh[tid] = 1.0f/sqrtf(rsum);
  }
  __syncthreads();
  for (int i=tid;i<3844;i+=256){
    int n=i/62, m=i-n*62;
    adj[(size_t)b*3844+i] = a[i]*dsh[n]*dsh[m];
  }
}

// ---------------- h_entry_pre / h_pool_pre = adj @ ow - bias, + node stats ----------------
__global__ __launch_bounds__(256) void k_gcn1(
    const float* __restrict__ adj, const float* __restrict__ ow,
    const float* __restrict__ entry_b, const float* __restrict__ pool_b,
    float* __restrict__ hE, float* __restrict__ hP,
    double* __restrict__ statE, double* __restrict__ statP)
{
  __shared__ float aL[3844];
  __shared__ float oL[5952];
  __shared__ float es[62], eq[62], ps[62], pq[62];
  int b = blockIdx.x, tid = threadIdx.x;
  for (int i=tid;i<3844;i+=256) aL[i]=adj[(size_t)b*3844+i];
  for (int i=tid;i<5952;i+=256) oL[i]=ow[(size_t)b*5952+i];
  if (tid<62){es[tid]=0.f;eq[tid]=0.f;ps[tid]=0.f;pq[tid]=0.f;}
  __syncthreads();
  for (int i=tid;i<5952;i+=256){
    int n=i/96, j=i-n*96;
    float v=0.f;
    for (int m=0;m<62;m++) v = fmaf(aL[n*62+m], oL[m*96+j], v);
    if (j<64){
      v -= entry_b[j];
      hE[((size_t)b*62+n)*64 + j] = v;
      atomicAdd(&es[n],v); atomicAdd(&eq[n],v*v);
    } else {
      int j2=j-64;
      v -= pool_b[j2];
      hP[((size_t)b*62+n)*32 + j2] = v;
      atomicAdd(&ps[n],v); atomicAdd(&pq[n],v*v);
    }
  }
  __syncthreads();
  if (tid<62){
    atomicAdd(&statE[tid*2],(double)es[tid]);
    atomicAdd(&statE[tid*2+1],(double)eq[tid]);
    atomicAdd(&statP[tid*2],(double)ps[tid]);
    atomicAdd(&statP[tid*2+1],(double)pq[tid]);
  }
}

// ---------------- normalize h_entry in place ----------------
__global__ __launch_bounds__(256) void k_bn_he(float* __restrict__ hE,
                                               const double* __restrict__ statE)
{
  int idx = blockIdx.x*256 + threadIdx.x;
  if (idx >= cB*62*64) return;
  int n = (idx>>6) % 62;
  double cnt = (double)cB*64;
  double m = statE[n*2]/cnt;
  double v = statE[n*2+1]/cnt - m*m;
  hE[idx] = (hE[idx]-(float)m) * (float)(1.0/sqrt(v+1e-5));
}

// ---------------- s_assign = softmax(bn(h_pool) @ pl_w + pl_b), + ent_loss ----------------
__global__ __launch_bounds__(256) void k_assign(
    const float* __restrict__ hP, const double* __restrict__ statP,
    const float* __restrict__ pl_w, const float* __restrict__ pl_b,
    float* __restrict__ sA, double* __restrict__ accs)
{
  int gid = blockIdx.x*256 + threadIdx.x;
  int r = gid >> 5, o = gid & 31;
  int n = r % 62;
  double cnt = (double)cB*32;
  double md = statP[n*2]/cnt;
  double vd = statP[n*2+1]/cnt - md*md;
  float m = (float)md, inv = (float)(1.0/sqrt(vd+1e-5));
  float y = pl_b[o];
  for (int j=0;j<32;j++){
    float z = (hP[(size_t)r*32+j]-m)*inv;
    y = fmaf(z, pl_w[j*32+o], y);
  }
  float mx = y;
  for (int d=16;d>0;d>>=1) mx = fmaxf(mx, __shfl_xor(mx,d,32));
  float e = expf(y-mx);
  float sum = e;
  for (int d=16;d>0;d>>=1) sum += __shfl_xor(sum,d,32);
  float p = e/sum;
  sA[(size_t)r*32+o] = p;
  float ent = -p*logf(p+1e-30f);
  for (int d=16;d>0;d>>=1) ent += __shfl_xor(ent,d,32);
  if (o==0) atomicAdd(&accs[1], (double)ent);
}

// ---------------- dense_diff_pool + embed GCN pre + link_loss ----------------
__global__ __launch_bounds__(256) void k_pool(
    const float* __restrict__ adj, const float* __restrict__ sA_g,
    const float* __restrict__ hE, const float* __restrict__ embed_w,
    const float* __restrict__ embed_b, float* __restrict__ hpre,
    double* __restrict__ statH, double* __restrict__ accs)
{
  __shared__ float aL[3844];
  __shared__ float sL[1984];
  __shared__ float hL[3968];   // later reused as e1[32*64]
  __shared__ float t1[1984];   // later reused as sT[32*62]
  __shared__ float xp[2048];
  __shared__ float ap[1024];
  __shared__ float red[256];
  __shared__ float ksum[32], ksq[32];
  float* e1 = hL;
  float* sT = t1;
  int b = blockIdx.x, tid = threadIdx.x;
  for (int i=tid;i<3844;i+=256) aL[i]=adj[(size_t)b*3844+i];
  for (int i=tid;i<1984;i+=256) sL[i]=sA_g[(size_t)b*1984+i];
  for (int i=tid;i<3968;i+=256) hL[i]=hE[(size_t)b*3968+i];
  if (tid<32){ksum[tid]=0.f;ksq[tid]=0.f;}
  __syncthreads();
  for (int i=tid;i<2048;i+=256){
    int k=i>>6, f=i&63;
    float v=0.f;
    for (int n=0;n<62;n++) v = fmaf(sL[n*32+k], hL[n*64+f], v);
    xp[i]=v;
  }
  for (int i=tid;i<1984;i+=256){
    int n=i>>5, k=i&31;
    float v=0.f;
    for (int m=0;m<62;m++) v = fmaf(aL[n*62+m], sL[m*32+k], v);
    t1[i]=v;
  }
  __syncthreads();
  for (int i=tid;i<1024;i+=256){
    int k=i>>5, l=i&31;
    float v=0.f;
    for (int n=0;n<62;n++) v = fmaf(sL[n*32+k], t1[n*32+l], v);
    ap[i]=v;
  }
  __syncthreads();
  for (int i=tid;i<1984;i+=256){
    int k=i/62, n=i-k*62;
    sT[k*62+n] = sL[n*32+k];
  }
  __syncthreads();
  float lacc=0.f;
  for (int i=tid;i<3844;i+=256){
    int n=i/62, m=i-n*62;
    float v=0.f;
    for (int k=0;k<32;k++) v = fmaf(sT[k*62+n], sT[k*62+m], v);
    float d = aL[i]-v+1e-30f;
    lacc = fmaf(d,d,lacc);
  }
  red[tid]=lacc; __syncthreads();
  for (int o=128;o>0;o>>=1){ if(tid<o) red[tid]+=red[tid+o]; __syncthreads(); }
  if (tid==0) atomicAdd(&accs[0], (double)red[0]);
  __syncthreads();
  for (int i=tid;i<2048;i+=256){
    int k=i>>6, f=i&63;
    float v=0.f;
    for (int l=0;l<32;l++) v = fmaf(ap[k*32+l], xp[l*64+f], v);
    e1[i]=v;
  }
  __syncthreads();
  for (int i=tid;i<2048;i+=256){
    int k=i>>6, j=i&63;
    float v=0.f;
    for (int f=0;f<64;f++) v = fmaf(e1[k*64+f], embed_w[f*64+j], v);
    v -= embed_b[j];
    hpre[(size_t)b*2048 + i] = v;
    atomicAdd(&ksum[k], v);
    atomicAdd(&ksq[k], v*v);
  }
  __syncthreads();
  if (tid<32){
    atomicAdd(&statH[tid*2],   (double)ksum[tid]);
    atomicAdd(&statH[tid*2+1], (double)ksq[tid]);
  }
}

// ---------------- reps + MLP head (pre final BN) ----------------
__global__ __launch_bounds__(128) void k_head(
    const float* __restrict__ hE, const float* __restrict__ hpre,
    const double* __restrict__ statH,
    const float* __restrict__ fc1_w, const float* __restrict__ fc1_b,
    const float* __restrict__ fc2_w, const float* __restrict__ fc2_b,
    const float* __restrict__ fc3_w, const float* __restrict__ fc3_b,
    float* __restrict__ o_pre)
{
  __shared__ float o1[128], y1[128], y2[64];
  __shared__ float mk[32], ik[32];
  int b = blockIdx.x, tid = threadIdx.x;
  if (tid<32){
    double cnt = 2048.0;
    double m = statH[tid*2]/cnt;
    double v = statH[tid*2+1]/cnt - m*m;
    mk[tid]=(float)m; ik[tid]=(float)(1.0/sqrt(v+1e-5));
  }
  __syncthreads();
  if (tid<64){
    float s1=0.f;
    for (int n=0;n<62;n++) s1 += hE[((size_t)b*62+n)*64+tid];
    o1[tid]=s1;
    float s2=0.f;
    for (int k=0;k<32;k++) s2 += (hpre[(size_t)b*2048 + k*64+tid]-mk[k])*ik[k];
    o1[64+tid]=s2;
  }
  __syncthreads();
  {
    float y = fc1_b[tid];
    for (int j=0;j<128;j++) y = fmaf(o1[j], fc1_w[j*128+tid], y);
    y1[tid] = fmaxf(y,0.f);
  }
  __syncthreads();
  if (tid<64){
    float z = fc2_b[tid];
    for (int j=0;j<128;j++) z = fmaf(y1[j], fc2_w[j*64+tid], z);
    y2[tid]=fmaxf(z,0.f);
  }
  __syncthreads();
  if (tid<4){
    float w = fc3_b[tid];
    for (int j=0;j<64;j++) w = fmaf(y2[j], fc3_w[j*4+tid], w);
    o_pre[b*4+tid]=w;
  }
}

// ---------------- final BN over batch + losses ----------------
__global__ void k_final(const float* __restrict__ o_pre, const double* __restrict__ accs,
                        float* __restrict__ out)
{
  int tid = threadIdx.x;
  if (tid<4){
    float s=0.f,q=0.f;
    for (int b=0;b<32;b++){ float v=o_pre[b*4+tid]; s+=v; q+=v*v; }
    float m = s*(1.f/32.f);
    float var = q*(1.f/32.f) - m*m;
    float inv = 1.0f/sqrtf(var+1e-5f);
    for (int b=0;b<32;b++) out[b*4+tid] = (o_pre[b*4+tid]-m)*inv;
  }
  if (tid==4) out[128] = (float)(sqrt(accs[0])/123008.0);
  if (tid==5) out[129] = (float)(accs[1]/1984.0);
}

// ---------------- workspace-too-small sentinel (diagnostic) ----------------
__global__ void k_wsfail(float* __restrict__ out, int n)
{
  int i = blockIdx.x*256 + threadIdx.x;
  if (i < n) out[i] = 12345.0f;
}

// ============================================================================
extern "C" void kernel_launch(void* const* d_in, const int* in_sizes, int n_in,
                              void* d_out, int out_size, void* d_ws, size_t ws_size,
                              hipStream_t stream)
{
  const float* x       = (const float*)d_in[0];
  const float* w1      = (const float*)d_in[1];
  const float* b1      = (const float*)d_in[2];
  const float* w2      = (const float*)d_in[3];
  const float* b2      = (const float*)d_in[4];
  const float* w3      = (const float*)d_in[5];
  const float* b3      = (const float*)d_in[6];
  const float* oxo_w   = (const float*)d_in[7];
  const float* oxo_b   = (const float*)d_in[8];
  const float* lf_w    = (const float*)d_in[9];
  const float* lf_b    = (const float*)d_in[10];
  const float* gadj    = (const float*)d_in[11];
  const float* entry_w = (const float*)d_in[12];
  const float* entry_b = (const float*)d_in[13];
  const float* pool_w  = (const float*)d_in[14];
  const float* pool_b  = (const float*)d_in[15];
  const float* pl_w    = (const float*)d_in[16];
  const float* pl_b    = (const float*)d_in[17];
  const float* embed_w = (const float*)d_in[18];
  const float* embed_b = (const float*)d_in[19];
  const float* fc1_w   = (const float*)d_in[20];
  const float* fc1_b   = (const float*)d_in[21];
  const float* fc2_w   = (const float*)d_in[22];
  const float* fc2_b   = (const float*)d_in[23];
  const float* fc3_w   = (const float*)d_in[24];
  const float* fc3_b   = (const float*)d_in[25];

  char* ws = (char*)d_ws;
  size_t off = 0;
  auto take = [&](size_t bytes){ size_t o = off; off = (off + bytes + 15) & ~(size_t)15; return o; };

  size_t feat_o = take(FEAT_N*4);          // conv logs; k_mix writes pooled rows in place
  size_t zstart = off;                     // ---- zeroed zone (atomic accumulators) ----
  size_t s_o     = take(S_N*4);
  size_t ow_o    = take(OW_N*4);
  size_t statC_o = take(124*8);
  size_t statE_o = take(124*8);
  size_t statP_o = take(124*8);
  size_t statH_o = take(64*8);
  size_t accs_o  = take(2*8);
  size_t zend = off;                       // ---- end zeroed zone ----
  size_t stat1_o = take(64*8);
  size_t stat2_o = take(64*8);
  size_t part1_o = take(PART_N*4);
  size_t part2_o = take(PART_N*4);
  size_t adj_o   = take(ADJ_N*4);
  size_t hE_o    = take(HE_N*4);
  size_t hP_o    = take(HP_N*4);
  size_t sA_o    = take(SA_N*4);
  size_t hpre_o  = take(HPRE_N*4);
  size_t opre_o  = take(128*4);
  size_t wpad_o  = take(WPAD_N*4);

  if (off > ws_size) {                     // diagnostic: ws too small
    k_wsfail<<<(out_size+255)/256, 256, 0, stream>>>((float*)d_out, out_size);
    return;
  }

  float*  feat  = (float*)(ws+feat_o);
  float*  s_g   = (float*)(ws+s_o);
  float*  ow_g  = (float*)(ws+ow_o);
  double* statC = (double*)(ws+statC_o);
  double* statE = (double*)(ws+statE_o);
  double* statP = (double*)(ws+statP_o);
  double* statH = (double*)(ws+statH_o);
  double* accs  = (double*)(ws+accs_o);
  double* stat1 = (double*)(ws+stat1_o);
  double* stat2 = (double*)(ws+stat2_o);
  float*  part1 = (float*)(ws+part1_o);
  float*  part2 = (float*)(ws+part2_o);
  float*  adj_g = (float*)(ws+adj_o);
  float*  hE_g  = (float*)(ws+hE_o);
  float*  hP_g  = (float*)(ws+hP_o);
  float*  sA_g  = (float*)(ws+sA_o);
  float*  hpre  = (float*)(ws+hpre_o);
  float*  opre  = (float*)(ws+opre_o);
  float*  wpad  = (float*)(ws+wpad_o);
  float*  out   = (float*)d_out;

  hipMemsetAsync(ws + zstart, 0, zend - zstart, stream);

  k_padw<<<26, 256, 0, stream>>>(w1, w2, w3, wpad);
  k_conv<<<cNBC, 256, 0, stream>>>(x, wpad, b1, b2, b3, feat, part1);
  k_reduce_stats<<<32, 256, 0, stream>>>(part1, stat1, cNBC, 32);
  k_mix<<<cNBC, 256, 0, stream>>>(feat, stat1, oxo_w, oxo_b, part2);
  k_reduce_stats<<<32, 256, 0, stream>>>(part2, stat2, cNBC, 32);
  k_lfstats<<<cNBC, 256, 0, stream>>>(feat, stat2, lf_w, lf_b, statC);
  k_gramow<<<cB*16, 256, 0, stream>>>(feat, stat2, lf_w, lf_b, statC, entry_w, pool_w, s_g, ow_g);
  k_adj<<<cB, 256, 0, stream>>>(s_g, gadj, adj_g);
  k_gcn1<<<cB, 256, 0, stream>>>(adj_g, ow_g, entry_b, pool_b, hE_g, hP_g, statE, statP);
  k_bn_he<<<(cB*62*64+255)/256, 256, 0, stream>>>(hE_g, statE);
  k_assign<<<(cB*62*32)/256, 256, 0, stream>>>(hP_g, statP, pl_w, pl_b, sA_g, accs);
  k_pool<<<cB, 256, 0, stream>>>(adj_g, sA_g, hE_g, embed_w, embed_b, hpre, statH, accs);
  k_head<<<cB, 128, 0, stream>>>(hE_g, hpre, statH, fc1_w, fc1_b, fc2_w, fc2_b, fc3_w, fc3_b, opre);
  k_final<<<1, 64, 0, stream>>>(opre, accs, out);
}

// Round 5
// 995.042 us; speedup vs baseline: 1.7790x; 1.0103x over previous
//
#include <hip/hip_runtime.h>
#include <math.h>

// ---------------- problem constants ----------------
constexpr int cB  = 32;     // batch
constexpr int cC  = 62;     // channels (graph nodes)
constexpr int cT  = 1024;   // time
constexpr int cNT = 32;     // temporal filters
constexpr int cLT = 708;    // concat conv-pool length (247+240+221)
constexpr int cLT2= 354;    // after avgpool(1,2)
constexpr int cFD = 11328;  // NT * 354
constexpr int cNBC = cB*cC; // 1984 blocks for per-(b,c) kernels

// element counts
constexpr size_t FEAT_N = (size_t)cB*cNT*cC*cLT;   // ~180 MB - conv logs, then in-place pooled mix
constexpr size_t P_N    = (size_t)cB*cC*cC;        // raw gram V V^T
constexpr size_t Q_N    = (size_t)cB*cC*96;        // raw V @ [entry_w|pool_w]
constexpr size_t R_N    = (size_t)cB*64;           // rowsums of V
constexpr size_t PART_N = (size_t)cNBC*64;
constexpr size_t ADJ_N  = P_N;
constexpr size_t HE_N   = (size_t)cB*cC*64;
constexpr size_t HP_N   = (size_t)cB*cC*32;
constexpr size_t SA_N   = HP_N;
constexpr size_t HPRE_N = (size_t)cB*32*64;
constexpr size_t WPAD_N = 32*28 + 32*52 + 32*128;  // 6656 padded weights

// ---------------- prep: pad conv weights + wcol[j] = sum_k W[k][j] ----------------
__global__ __launch_bounds__(256) void k_prep(
    const float* __restrict__ w1, const float* __restrict__ w2,
    const float* __restrict__ w3, const float* __restrict__ entry_w,
    const float* __restrict__ pool_w, float* __restrict__ wpad,
    float* __restrict__ wcol)
{
  int blk = blockIdx.x, tid = threadIdx.x;
  if (blk < 26){
    int i = blk*256 + tid;
    if (i < 896){ int t=i/28, k=i-t*28; wpad[i] = (k<25) ? w1[t*25+k] : 0.f; }
    else if (i < 2560){ int j=i-896; int t=j/52, k=j-t*52; wpad[i] = (k<51) ? w2[t*51+k] : 0.f; }
    else if (i < 6656){ wpad[i] = w3[i-2560]; }
  } else {
    int j = blk - 26;          // 0..95
    float s = 0.f;
    if (j < 64){ for (int k=tid;k<cFD;k+=256) s += entry_w[(size_t)k*64 + j]; }
    else       { for (int k=tid;k<cFD;k+=256) s += pool_w[(size_t)k*32 + (j-64)]; }
    __shared__ float red[256];
    red[tid]=s; __syncthreads();
    for (int o=128;o>0;o>>=1){ if(tid<o) red[tid]+=red[tid+o]; __syncthreads(); }
    if (tid==0) wcol[j] = red[0];
  }
}

// ---------------- conv core: 4 filters x 4 positions per lane, rolling float4 window ----------------
template<int K4, int L, int G>
__device__ __forceinline__ void conv4(
    const float* xs, const float* __restrict__ wg, const float* __restrict__ bg,
    float* pt, int tid)
{
  if (tid >= G) return;
  int pos = 4*tid;
  float4 c = *(const float4*)&xs[pos];
  float x0=c.x, x1=c.y, x2=c.z, x3=c.w;
  float a[4][4];
  #pragma unroll
  for (int f=0;f<4;f++){ float bv=bg[f]; a[f][0]=bv; a[f][1]=bv; a[f][2]=bv; a[f][3]=bv; }
  #pragma unroll 4
  for (int i=0;i<K4;i+=4){
    float4 n = *(const float4*)&xs[pos+4+i];    // 16B-aligned, 16B/lane stride
    #pragma unroll
    for (int f=0;f<4;f++){
      const float* w = wg + f*K4 + i;           // wave-uniform -> scalar loads
      float w0=w[0], w1=w[1], w2=w[2], w3=w[3];
      a[f][0]=fmaf(x0,w0,a[f][0]); a[f][1]=fmaf(x1,w0,a[f][1]); a[f][2]=fmaf(x2,w0,a[f][2]); a[f][3]=fmaf(x3,w0,a[f][3]);
      a[f][0]=fmaf(x1,w1,a[f][0]); a[f][1]=fmaf(x2,w1,a[f][1]); a[f][2]=fmaf(x3,w1,a[f][2]); a[f][3]=fmaf(n.x,w1,a[f][3]);
      a[f][0]=fmaf(x2,w2,a[f][0]); a[f][1]=fmaf(x3,w2,a[f][1]); a[f][2]=fmaf(n.x,w2,a[f][2]); a[f][3]=fmaf(n.y,w2,a[f][3]);
      a[f][0]=fmaf(x3,w3,a[f][0]); a[f][1]=fmaf(n.x,w3,a[f][1]); a[f][2]=fmaf(n.y,w3,a[f][2]); a[f][3]=fmaf(n.z,w3,a[f][3]);
    }
    x0=n.x; x1=n.y; x2=n.z; x3=n.w;
  }
  #pragma unroll
  for (int f=0;f<4;f++){
    float p = (pos   < L ? a[f][0]*a[f][0] : 0.f)
            + (pos+1 < L ? a[f][1]*a[f][1] : 0.f)
            + (pos+2 < L ? a[f][2]*a[f][2] : 0.f)
            + (pos+3 < L ? a[f][3]*a[f][3] : 0.f);
    pt[f*256 + tid] = p;
  }
}

__global__ __launch_bounds__(256) void k_conv(
    const float* __restrict__ x,
    const float* __restrict__ wpad,
    const float* __restrict__ b1, const float* __restrict__ b2, const float* __restrict__ b3,
    float* __restrict__ feat, float* __restrict__ part1)
{
  __shared__ float xs[1152];
  __shared__ float pt1[1024], pt2[1024], pt3[1024];
  __shared__ float tsum[32], tsq[32];
  int b = blockIdx.x / cC, c = blockIdx.x % cC;
  int tid = threadIdx.x;
  for (int i=tid;i<1152;i+=256) xs[i] = (i<1024) ? x[(size_t)(b*cC+c)*cT + i] : 0.f;
  if (tid<32){ tsum[tid]=0.f; tsq[tid]=0.f; }
  for (int t0=0; t0<32; t0+=4){
    __syncthreads();
    conv4<28,1000,250>(xs, wpad + t0*28,        b1+t0, pt1, tid);
    conv4<52,974,244> (xs, wpad + 896 + t0*52,  b2+t0, pt2, tid);
    conv4<128,897,225>(xs, wpad + 2560 + t0*128,b3+t0, pt3, tid);
    __syncthreads();
    size_t base0 = ((size_t)(b*cNT+t0)*cC + c)*cLT;
    float val[4]={0.f,0.f,0.f,0.f}, vsq[4]={0.f,0.f,0.f,0.f};
    if (tid<247){
      #pragma unroll
      for (int f=0;f<4;f++){
        float p = (pt1[f*256+tid]+pt1[f*256+tid+1]+pt1[f*256+tid+2]+pt1[f*256+tid+3])*(1.f/16.f);
        float lv = __logf(p);
        feat[base0 + (size_t)f*cC*cLT + tid] = lv;
        val[f]+=lv; vsq[f]+=lv*lv;
      }
    }
    if (tid<240){
      #pragma unroll
      for (int f=0;f<4;f++){
        float p = (pt2[f*256+tid]+pt2[f*256+tid+1]+pt2[f*256+tid+2]+pt2[f*256+tid+3])*(1.f/16.f);
        float lv = __logf(p);
        feat[base0 + (size_t)f*cC*cLT + 247 + tid] = lv;
        val[f]+=lv; vsq[f]+=lv*lv;
      }
    }
    if (tid<221){
      #pragma unroll
      for (int f=0;f<4;f++){
        float p = (pt3[f*256+tid]+pt3[f*256+tid+1]+pt3[f*256+tid+2]+pt3[f*256+tid+3])*(1.f/16.f);
        float lv = __logf(p);
        feat[base0 + (size_t)f*cC*cLT + 487 + tid] = lv;
        val[f]+=lv; vsq[f]+=lv*lv;
      }
    }
    #pragma unroll
    for (int f=0;f<4;f++){
      float v=val[f], q=vsq[f];
      #pragma unroll
      for (int o=32;o>0;o>>=1){ v += __shfl_down(v,o,64); q += __shfl_down(q,o,64); }
      if ((tid&63)==0){ atomicAdd(&tsum[t0+f], v); atomicAdd(&tsq[t0+f], q); }
    }
  }
  __syncthreads();
  if (tid<32){
    part1[(size_t)blockIdx.x*64 + tid*2]   = tsum[tid];
    part1[(size_t)blockIdx.x*64 + tid*2+1] = tsq[tid];
  }
}

// ---------------- partial-stat reduction: [nblk][nch][2] f32 -> [nch][2] f64 ----------------
__global__ __launch_bounds__(256) void k_reduce_stats(
    const float* __restrict__ part, double* __restrict__ stat, int nblk, int nch)
{
  int ch = blockIdx.x, tid = threadIdx.x;
  double s=0,q=0;
  for (int i=tid;i<nblk;i+=256){
    s += (double)part[(size_t)i*nch*2 + ch*2];
    q += (double)part[(size_t)i*nch*2 + ch*2 + 1];
  }
  __shared__ double ls[256], lq[256];
  ls[tid]=s; lq[tid]=q; __syncthreads();
  for (int o=128;o>0;o>>=1){ if(tid<o){ls[tid]+=ls[tid+o]; lq[tid]+=lq[tid+o];} __syncthreads(); }
  if (tid==0){ stat[ch*2]=ls[0]; stat[ch*2+1]=lq[0]; }
}

// ---------------- BN_t + 1x1 conv + leaky + avgpool(1,2)  --- IN-PLACE, conflict-free ----------------
// o = tid>>3 fixed per thread -> oxo weights live in 32 VGPRs. ft padded to stride 122 so the
// float2 reads have 8 unique broadcast addresses per wave (conflict-free). Writes staged via LDS.
__global__ __launch_bounds__(256) void k_mix(
    float* __restrict__ feat, const double* __restrict__ stat1,
    const float* __restrict__ oxo_w, const float* __restrict__ oxo_b,
    float* __restrict__ part2)
{
  __shared__ float ft[32*122];
  __shared__ float vout[32*60];
  __shared__ float mvm[32], mvi[32];
  __shared__ float osum[32], osq[32];
  int b = blockIdx.x / cC, c = blockIdx.x % cC;
  int tid = threadIdx.x;
  int o = tid >> 3, lg = tid & 7;
  float wreg[32];
  #pragma unroll
  for (int t=0;t<32;t+=4){
    float4 w4 = *(const float4*)&oxo_w[o*32+t];
    wreg[t]=w4.x; wreg[t+1]=w4.y; wreg[t+2]=w4.z; wreg[t+3]=w4.w;
  }
  if (tid<32){
    double cnt = (double)cB*cC*cLT;
    double m = stat1[tid*2]/cnt;
    double v = stat1[tid*2+1]/cnt - m*m;
    mvm[tid] = (float)m;
    mvi[tid] = (float)(1.0/sqrt(v+1e-5));
    osum[tid]=0.f; osq[tid]=0.f;
  }
  float ob = oxo_b[o];
  float accs=0.f, accq=0.f;
  for (int ch=0; ch<6; ch++){
    __syncthreads();                       // ft/vout safe to overwrite; mvm visible (ch=0)
    int l0 = ch*118;
    for (int i=tid;i<32*118;i+=256){
      int t = i/118, l = i-t*118;
      ft[t*122+l] = (feat[((size_t)(b*cNT+t)*cC + c)*cLT + l0 + l] - mvm[t]) * mvi[t];
    }
    __syncthreads();
    for (int l2=lg; l2<59; l2+=8){
      float m0=ob, m1=ob;
      #pragma unroll
      for (int t=0;t<32;t++){
        float2 f2 = *(const float2*)&ft[t*122 + 2*l2];
        m0 = fmaf(f2.x, wreg[t], m0);
        m1 = fmaf(f2.y, wreg[t], m1);
      }
      m0 = m0>0.f ? m0 : 0.01f*m0;
      m1 = m1>0.f ? m1 : 0.01f*m1;
      float v = 0.5f*(m0+m1);
      vout[o*60 + l2] = v;
      accs += v; accq += v*v;
    }
    __syncthreads();
    for (int i=tid;i<1888;i+=256){
      int o2 = i/59, l2 = i - o2*59;
      feat[((size_t)(b*cNT+o2)*cC + c)*cLT + ch*59 + l2] = vout[o2*60+l2];
    }
  }
  atomicAdd(&osum[o], accs);
  atomicAdd(&osq[o], accq);
  __syncthreads();
  if (tid<32){
    part2[(size_t)blockIdx.x*64 + tid*2]   = osum[tid];
    part2[(size_t)blockIdx.x*64 + tid*2+1] = osq[tid];
  }
}

// ---------------- raw gram/ow/rowsum: P = V V^T, Q = V W, r = V 1  (no statC needed) ----------------
__global__ __launch_bounds__(256) void k_gramow(
    const float* __restrict__ featbuf, const double* __restrict__ stat2,
    const float* __restrict__ lf_w, const float* __restrict__ lf_b,
    const float* __restrict__ entry_w, const float* __restrict__ pool_w,
    float* __restrict__ P, float* __restrict__ Q, float* __restrict__ r_g)
{
  __shared__ float lt[64*68];
  __shared__ float lw[64*100];
  __shared__ float a_s[32], b_s[32];
  __shared__ float lbs[64];
  int b = blockIdx.x >> 4, ks = blockIdx.x & 15;
  int tid = threadIdx.x;
  if (tid<32){
    double cnt = (double)cB*cC*cLT2;
    double m = stat2[tid*2]/cnt;
    double v = stat2[tid*2+1]/cnt - m*m;
    float inv = (float)(1.0/sqrt(v+1e-5));
    a_s[tid] = inv;
    b_s[tid] = -(float)m * inv;
  }
  if (tid<64) lbs[tid] = (tid<62) ? lf_b[tid] : 0.f;
  float accG[4][4] = {{0.f}};
  float accO[4][6] = {{0.f}};
  float accR[4]    = {0.f,0.f,0.f,0.f};
  int n0 = (tid>>4)<<2;
  int mg = (tid&15)<<2;
  int jo = (tid&15)*6;
  int kk = tid & 63, nr = tid >> 6;
  for (int tile=ks; tile<177; tile+=16){
    int k0 = tile<<6;
    int f = k0 + kk, t = f/cLT2, l2 = f - t*cLT2;
    __syncthreads();
    for (int n=nr; n<64; n+=4){
      float v = 0.f;
      if (n<62){
        float raw = featbuf[((size_t)(b*cNT+t)*cC + n)*cLT + l2];
        float z = fmaf(raw, a_s[t], b_s[t]);
        v = fmaxf(fmaf(z, lf_w[(size_t)n*cFD + f], -lbs[n]), 0.f);
      }
      lt[kk*68 + n] = v;
    }
    for (int i=tid;i<6144;i+=256){
      int kw = i/96, j = i-kw*96;
      float wv = (j<64) ? entry_w[(size_t)(k0+kw)*64 + j] : pool_w[(size_t)(k0+kw)*32 + (j-64)];
      lw[kw*100 + j] = wv;
    }
    __syncthreads();
    #pragma unroll 4
    for (int k=0;k<64;k++){
      const float4 av = *(const float4*)&lt[k*68 + n0];
      const float4 bv = *(const float4*)&lt[k*68 + mg];
      const float2 w0 = *(const float2*)&lw[k*100+jo];
      const float2 w1 = *(const float2*)&lw[k*100+jo+2];
      const float2 w2 = *(const float2*)&lw[k*100+jo+4];
      float avv[4] = {av.x,av.y,av.z,av.w};
      float bvv[4] = {bv.x,bv.y,bv.z,bv.w};
      float wv[6]  = {w0.x,w0.y,w1.x,w1.y,w2.x,w2.y};
      #pragma unroll
      for (int i=0;i<4;i++){
        accR[i] += avv[i];
        #pragma unroll
        for (int j=0;j<4;j++) accG[i][j] = fmaf(avv[i], bvv[j], accG[i][j]);
        #pragma unroll
        for (int j=0;j<6;j++) accO[i][j] = fmaf(avv[i], wv[j], accO[i][j]);
      }
    }
  }
  for (int i=0;i<4;i++) if (n0+i<62){
    for (int j=0;j<4;j++) if (mg+j<62)
      atomicAdd(&P[((size_t)b*cC + n0+i)*cC + mg+j], accG[i][j]);
    for (int j=0;j<6;j++)
      atomicAdd(&Q[((size_t)b*cC + n0+i)*96 + jo+j], accO[i][j]);
  }
  if ((tid&15)==0)
    for (int i=0;i<4;i++) if (n0+i<62)
      atomicAdd(&r_g[(size_t)b*64 + n0+i], accR[i]);
}

// ---------------- statC from P diag + rowsums ----------------
__global__ void k_statC(const float* __restrict__ P, const float* __restrict__ r_g,
                        float* __restrict__ mCf, float* __restrict__ iCf)
{
  int n = threadIdx.x;
  if (n >= 62) return;
  double S=0, SQ=0;
  for (int b=0;b<32;b++){
    S  += (double)r_g[(size_t)b*64 + n];
    SQ += (double)P[((size_t)b*cC + n)*cC + n];
  }
  double cnt = (double)cB*cFD;
  double m = S/cnt, var = SQ/cnt - m*m;
  mCf[n] = (float)m;
  iCf[n] = (float)(1.0/sqrt(var+1e-5));
}

// ---------------- adjacency: rank-1-corrected gram -> relu -> +I -> sym normalize ----------------
__global__ __launch_bounds__(256) void k_adj(
    const float* __restrict__ P, const float* __restrict__ r_g,
    const float* __restrict__ mCf, const float* __restrict__ iCf,
    const float* __restrict__ gadj, float* __restrict__ adj)
{
  __shared__ float a[3844];
  __shared__ float dsh[62];
  __shared__ float rL[62], mL[62], iL[62];
  int b = blockIdx.x, tid = threadIdx.x;
  if (tid<62){ rL[tid]=r_g[(size_t)b*64+tid]; mL[tid]=mCf[tid]; iL[tid]=iCf[tid]; }
  __syncthreads();
  for (int i=tid;i<3844;i+=256){
    int n=i/62, m=i-n*62;
    float sv = (P[(size_t)b*3844+i] - mL[n]*rL[m] - mL[m]*rL[n] + (float)cFD*mL[n]*mL[m]) * iL[n]*iL[m];
    float g = gadj[n*62+m] + gadj[m*62+n];
    float v = sv*g;
    v = v>0.f ? v : 0.f;
    if (n==m) v += 1.f;
    a[i]=v;
  }
  __syncthreads();
  if (tid<62){
    float rsum=0.f;
    for (int m=0;m<62;m++) rsum += a[tid*62+m];
    if (rsum==0.f) rsum=1.f;
    dsh[tid] = 1.0f/sqrtf(rsum);
  }
  __syncthreads();
  for (int i=tid;i<3844;i+=256){
    int n=i/62, m=i-n*62;
    adj[(size_t)b*3844+i] = a[i]*dsh[n]*dsh[m];
  }
}

// ---------------- hE/hP = adj @ ow - bias (ow corrected in loader), + node stats ----------------
__global__ __launch_bounds__(256) void k_gcn1(
    const float* __restrict__ adj, const float* __restrict__ Q,
    const float* __restrict__ mCf, const float* __restrict__ iCf,
    const float* __restrict__ wcol,
    const float* __restrict__ entry_b, const float* __restrict__ pool_b,
    float* __restrict__ hE, float* __restrict__ hP,
    double* __restrict__ statE, double* __restrict__ statP)
{
  __shared__ float aL[3844];
  __shared__ float oL[5952];
  __shared__ float mL[62], iL[62], wcL[96];
  __shared__ float es[62], eq[62], ps[62], pq[62];
  int b = blockIdx.x, tid = threadIdx.x;
  if (tid<62){ mL[tid]=mCf[tid]; iL[tid]=iCf[tid]; }
  if (tid>=64 && tid<160) wcL[tid-64]=wcol[tid-64];
  if (tid>=192 && tid<254){ es[tid-192]=0.f; eq[tid-192]=0.f; ps[tid-192]=0.f; pq[tid-192]=0.f; }
  __syncthreads();
  for (int i=tid;i<3844;i+=256) aL[i]=adj[(size_t)b*3844+i];
  for (int i=tid;i<5952;i+=256){
    int m=i/96, j=i-m*96;
    oL[i] = (Q[(size_t)b*5952+i] - mL[m]*wcL[j]) * iL[m];
  }
  __syncthreads();
  for (int i=tid;i<5952;i+=256){
    int n=i/96, j=i-n*96;
    float v=0.f;
    for (int m=0;m<62;m++) v = fmaf(aL[n*62+m], oL[m*96+j], v);
    if (j<64){
      v -= entry_b[j];
      hE[((size_t)b*62+n)*64 + j] = v;
      atomicAdd(&es[n],v); atomicAdd(&eq[n],v*v);
    } else {
      int j2=j-64;
      v -= pool_b[j2];
      hP[((size_t)b*62+n)*32 + j2] = v;
      atomicAdd(&ps[n],v); atomicAdd(&pq[n],v*v);
    }
  }
  __syncthreads();
  if (tid<62){
    atomicAdd(&statE[tid*2],(double)es[tid]);
    atomicAdd(&statE[tid*2+1],(double)eq[tid]);
    atomicAdd(&statP[tid*2],(double)ps[tid]);
    atomicAdd(&statP[tid*2+1],(double)pq[tid]);
  }
}

// ---------------- merged: bn(h_entry) in place + s_assign softmax + ent_loss ----------------
__global__ __launch_bounds__(256) void k_bnassign(
    float* __restrict__ hE, const double* __restrict__ statE,
    const float* __restrict__ hP, const double* __restrict__ statP,
    const float* __restrict__ pl_w, const float* __restrict__ pl_b,
    float* __restrict__ sA, double* __restrict__ accs)
{
  int blk = blockIdx.x, tid = threadIdx.x;
  if (blk < 496){
    int idx = blk*256 + tid;
    if (idx >= cB*62*64) return;
    int n = (idx>>6) % 62;
    double cnt = (double)cB*64;
    double m = statE[n*2]/cnt;
    double v = statE[n*2+1]/cnt - m*m;
    hE[idx] = (hE[idx]-(float)m) * (float)(1.0/sqrt(v+1e-5));
  } else {
    int gid = (blk-496)*256 + tid;
    int r = gid >> 5, o = gid & 31;
    int n = r % 62;
    double cnt = (double)cB*32;
    double md = statP[n*2]/cnt;
    double vd = statP[n*2+1]/cnt - md*md;
    float m = (float)md, inv = (float)(1.0/sqrt(vd+1e-5));
    float y = pl_b[o];
    for (int j=0;j<32;j++){
      float z = (hP[(size_t)r*32+j]-m)*inv;
      y = fmaf(z, pl_w[j*32+o], y);
    }
    float mx = y;
    for (int d=16;d>0;d>>=1) mx = fmaxf(mx, __shfl_xor(mx,d,32));
    float e = expf(y-mx);
    float sum = e;
    for (int d=16;d>0;d>>=1) sum += __shfl_xor(sum,d,32);
    float p = e/sum;
    sA[(size_t)r*32+o] = p;
    float ent = -p*logf(p+1e-30f);
    for (int d=16;d>0;d>>=1) ent += __shfl_xor(ent,d,32);
    if (o==0) atomicAdd(&accs[1], (double)ent);
  }
}

// ---------------- dense_diff_pool + embed GCN pre + link_loss ----------------
__global__ __launch_bounds__(256) void k_pool(
    const float* __restrict__ adj, const float* __restrict__ sA_g,
    const float* __restrict__ hE, const float* __restrict__ embed_w,
    const float* __restrict__ embed_b, float* __restrict__ hpre,
    double* __restrict__ statH, double* __restrict__ accs)
{
  __shared__ float aL[3844];
  __shared__ float sL[1984];
  __shared__ float hL[3968];   // later reused as e1[32*64]
  __shared__ float t1[1984];   // later reused as sT[32*62]
  __shared__ float xp[2048];
  __shared__ float ap[1024];
  __shared__ float red[256];
  __shared__ float ksum[32], ksq[32];
  float* e1 = hL;
  float* sT = t1;
  int b = blockIdx.x, tid = threadIdx.x;
  for (int i=tid;i<3844;i+=256) aL[i]=adj[(size_t)b*3844+i];
  for (int i=tid;i<1984;i+=256) sL[i]=sA_g[(size_t)b*1984+i];
  for (int i=tid;i<3968;i+=256) hL[i]=hE[(size_t)b*3968+i];
  if (tid<32){ksum[tid]=0.f;ksq[tid]=0.f;}
  __syncthreads();
  for (int i=tid;i<2048;i+=256){
    int k=i>>6, f=i&63;
    float v=0.f;
    for (int n=0;n<62;n++) v = fmaf(sL[n*32+k], hL[n*64+f], v);
    xp[i]=v;
  }
  for (int i=tid;i<1984;i+=256){
    int n=i>>5, k=i&31;
    float v=0.f;
    for (int m=0;m<62;m++) v = fmaf(aL[n*62+m], sL[m*32+k], v);
    t1[i]=v;
  }
  __syncthreads();
  for (int i=tid;i<1024;i+=256){
    int k=i>>5, l=i&31;
    float v=0.f;
    for (int n=0;n<62;n++) v = fmaf(sL[n*32+k], t1[n*32+l], v);
    ap[i]=v;
  }
  __syncthreads();
  for (int i=tid;i<1984;i+=256){
    int k=i/62, n=i-k*62;
    sT[k*62+n] = sL[n*32+k];
  }
  __syncthreads();
  float lacc=0.f;
  for (int i=tid;i<3844;i+=256){
    int n=i/62, m=i-n*62;
    float v=0.f;
    for (int k=0;k<32;k++) v = fmaf(sT[k*62+n], sT[k*62+m], v);
    float d = aL[i]-v+1e-30f;
    lacc = fmaf(d,d,lacc);
  }
  red[tid]=lacc; __syncthreads();
  for (int o=128;o>0;o>>=1){ if(tid<o) red[tid]+=red[tid+o]; __syncthreads(); }
  if (tid==0) atomicAdd(&accs[0], (double)red[0]);
  __syncthreads();
  for (int i=tid;i<2048;i+=256){
    int k=i>>6, f=i&63;
    float v=0.f;
    for (int l=0;l<32;l++) v = fmaf(ap[k*32+l], xp[l*64+f], v);
    e1[i]=v;
  }
  __syncthreads();
  for (int i=tid;i<2048;i+=256){
    int k=i>>6, j=i&63;
    float v=0.f;
    for (int f=0;f<64;f++) v = fmaf(e1[k*64+f], embed_w[f*64+j], v);
    v -= embed_b[j];
    hpre[(size_t)b*2048 + i] = v;
    atomicAdd(&ksum[k], v);
    atomicAdd(&ksq[k], v*v);
  }
  __syncthreads();
  if (tid<32){
    atomicAdd(&statH[tid*2],   (double)ksum[tid]);
    atomicAdd(&statH[tid*2+1], (double)ksq[tid]);
  }
}

// ---------------- reps + MLP head (pre final BN) ----------------
__global__ __launch_bounds__(128) void k_head(
    const float* __restrict__ hE, const float* __restrict__ hpre,
    const double* __restrict__ statH,
    const float* __restrict__ fc1_w, const float* __restrict__ fc1_b,
    const float* __restrict__ fc2_w, const float* __restrict__ fc2_b,
    const float* __restrict__ fc3_w, const float* __restrict__ fc3_b,
    float* __restrict__ o_pre)
{
  __shared__ float o1[128], y1[128], y2[64];
  __shared__ float mk[32], ik[32];
  int b = blockIdx.x, tid = threadIdx.x;
  if (tid<32){
    double cnt = 2048.0;
    double m = statH[tid*2]/cnt;
    double v = statH[tid*2+1]/cnt - m*m;
    mk[tid]=(float)m; ik[tid]=(float)(1.0/sqrt(v+1e-5));
  }
  __syncthreads();
  if (tid<64){
    float s1=0.f;
    for (int n=0;n<62;n++) s1 += hE[((size_t)b*62+n)*64+tid];
    o1[tid]=s1;
    float s2=0.f;
    for (int k=0;k<32;k++) s2 += (hpre[(size_t)b*2048 + k*64+tid]-mk[k])*ik[k];
    o1[64+tid]=s2;
  }
  __syncthreads();
  {
    float y = fc1_b[tid];
    for (int j=0;j<128;j++) y = fmaf(o1[j], fc1_w[j*128+tid], y);
    y1[tid] = fmaxf(y,0.f);
  }
  __syncthreads();
  if (tid<64){
    float z = fc2_b[tid];
    for (int j=0;j<128;j++) z = fmaf(y1[j], fc2_w[j*64+tid], z);
    y2[tid]=fmaxf(z,0.f);
  }
  __syncthreads();
  if (tid<4){
    float w = fc3_b[tid];
    for (int j=0;j<64;j++) w = fmaf(y2[j], fc3_w[j*4+tid], w);
    o_pre[b*4+tid]=w;
  }
}

// ---------------- final BN over batch + losses ----------------
__global__ void k_final(const float* __restrict__ o_pre, const double* __restrict__ accs,
                        float* __restrict__ out)
{
  int tid = threadIdx.x;
  if (tid<4){
    float s=0.f,q=0.f;
    for (int b=0;b<32;b++){ float v=o_pre[b*4+tid]; s+=v; q+=v*v; }
    float m = s*(1.f/32.f);
    float var = q*(1.f/32.f) - m*m;
    float inv = 1.0f/sqrtf(var+1e-5f);
    for (int b=0;b<32;b++) out[b*4+tid] = (o_pre[b*4+tid]-m)*inv;
  }
  if (tid==4) out[128] = (float)(sqrt(accs[0])/123008.0);
  if (tid==5) out[129] = (float)(accs[1]/1984.0);
}

// ---------------- workspace-too-small sentinel (diagnostic) ----------------
__global__ void k_wsfail(float* __restrict__ out, int n)
{
  int i = blockIdx.x*256 + threadIdx.x;
  if (i < n) out[i] = 12345.0f;
}

// ============================================================================
extern "C" void kernel_launch(void* const* d_in, const int* in_sizes, int n_in,
                              void* d_out, int out_size, void* d_ws, size_t ws_size,
                              hipStream_t stream)
{
  const float* x       = (const float*)d_in[0];
  const float* w1      = (const float*)d_in[1];
  const float* b1      = (const float*)d_in[2];
  const float* w2      = (const float*)d_in[3];
  const float* b2      = (const float*)d_in[4];
  const float* w3      = (const float*)d_in[5];
  const float* b3      = (const float*)d_in[6];
  const float* oxo_w   = (const float*)d_in[7];
  const float* oxo_b   = (const float*)d_in[8];
  const float* lf_w    = (const float*)d_in[9];
  const float* lf_b    = (const float*)d_in[10];
  const float* gadj    = (const float*)d_in[11];
  const float* entry_w = (const float*)d_in[12];
  const float* entry_b = (const float*)d_in[13];
  const float* pool_w  = (const float*)d_in[14];
  const float* pool_b  = (const float*)d_in[15];
  const float* pl_w    = (const float*)d_in[16];
  const float* pl_b    = (const float*)d_in[17];
  const float* embed_w = (const float*)d_in[18];
  const float* embed_b = (const float*)d_in[19];
  const float* fc1_w   = (const float*)d_in[20];
  const float* fc1_b   = (const float*)d_in[21];
  const float* fc2_w   = (const float*)d_in[22];
  const float* fc2_b   = (const float*)d_in[23];
  const float* fc3_w   = (const float*)d_in[24];
  const float* fc3_b   = (const float*)d_in[25];

  char* ws = (char*)d_ws;
  size_t off = 0;
  auto take = [&](size_t bytes){ size_t o = off; off = (off + bytes + 15) & ~(size_t)15; return o; };

  size_t feat_o = take(FEAT_N*4);          // conv logs; k_mix writes pooled rows in place
  size_t zstart = off;                     // ---- zeroed zone (atomic accumulators) ----
  size_t P_o     = take(P_N*4);
  size_t Q_o     = take(Q_N*4);
  size_t r_o     = take(R_N*4);
  size_t statE_o = take(124*8);
  size_t statP_o = take(124*8);
  size_t statH_o = take(64*8);
  size_t accs_o  = take(2*8);
  size_t zend = off;                       // ---- end zeroed zone ----
  size_t stat1_o = take(64*8);
  size_t stat2_o = take(64*8);
  size_t mCf_o   = take(64*4);
  size_t iCf_o   = take(64*4);
  size_t wcol_o  = take(96*4);
  size_t part1_o = take(PART_N*4);
  size_t part2_o = take(PART_N*4);
  size_t adj_o   = take(ADJ_N*4);
  size_t hE_o    = take(HE_N*4);
  size_t hP_o    = take(HP_N*4);
  size_t sA_o    = take(SA_N*4);
  size_t hpre_o  = take(HPRE_N*4);
  size_t opre_o  = take(128*4);
  size_t wpad_o  = take(WPAD_N*4);

  if (off > ws_size) {                     // diagnostic: ws too small
    k_wsfail<<<(out_size+255)/256, 256, 0, stream>>>((float*)d_out, out_size);
    return;
  }

  float*  feat  = (float*)(ws+feat_o);
  float*  P_g   = (float*)(ws+P_o);
  float*  Q_g   = (float*)(ws+Q_o);
  float*  r_g   = (float*)(ws+r_o);
  double* statE = (double*)(ws+statE_o);
  double* statP = (double*)(ws+statP_o);
  double* statH = (double*)(ws+statH_o);
  double* accs  = (double*)(ws+accs_o);
  double* stat1 = (double*)(ws+stat1_o);
  double* stat2 = (double*)(ws+stat2_o);
  float*  mCf   = (float*)(ws+mCf_o);
  float*  iCf   = (float*)(ws+iCf_o);
  float*  wcol  = (float*)(ws+wcol_o);
  float*  part1 = (float*)(ws+part1_o);
  float*  part2 = (float*)(ws+part2_o);
  float*  adj_g = (float*)(ws+adj_o);
  float*  hE_g  = (float*)(ws+hE_o);
  float*  hP_g  = (float*)(ws+hP_o);
  float*  sA_g  = (float*)(ws+sA_o);
  float*  hpre  = (float*)(ws+hpre_o);
  float*  opre  = (float*)(ws+opre_o);
  float*  wpad  = (float*)(ws+wpad_o);
  float*  out   = (float*)d_out;

  hipMemsetAsync(ws + zstart, 0, zend - zstart, stream);

  k_prep<<<122, 256, 0, stream>>>(w1, w2, w3, entry_w, pool_w, wpad, wcol);
  k_conv<<<cNBC, 256, 0, stream>>>(x, wpad, b1, b2, b3, feat, part1);
  k_reduce_stats<<<32, 256, 0, stream>>>(part1, stat1, cNBC, 32);
  k_mix<<<cNBC, 256, 0, stream>>>(feat, stat1, oxo_w, oxo_b, part2);
  k_reduce_stats<<<32, 256, 0, stream>>>(part2, stat2, cNBC, 32);
  k_gramow<<<cB*16, 256, 0, stream>>>(feat, stat2, lf_w, lf_b, entry_w, pool_w, P_g, Q_g, r_g);
  k_statC<<<1, 64, 0, stream>>>(P_g, r_g, mCf, iCf);
  k_adj<<<cB, 256, 0, stream>>>(P_g, r_g, mCf, iCf, gadj, adj_g);
  k_gcn1<<<cB, 256, 0, stream>>>(adj_g, Q_g, mCf, iCf, wcol, entry_b, pool_b, hE_g, hP_g, statE, statP);
  k_bnassign<<<496+248, 256, 0, stream>>>(hE_g, statE, hP_g, statP, pl_w, pl_b, sA_g, accs);
  k_pool<<<cB, 256, 0, stream>>>(adj_g, sA_g, hE_g, embed_w, embed_b, hpre, statH, accs);
  k_head<<<cB, 128, 0, stream>>>(hE_g, hpre, statH, fc1_w, fc1_b, fc2_w, fc2_b, fc3_w, fc3_b, opre);
  k_final<<<1, 64, 0, stream>>>(opre, accs, out);
}